// Round 5
// baseline (571.578 us; speedup 1.0000x reference)
//
#include <hip/hip_runtime.h>
#include <cmath>

#define H_ 256
#define W_ 256
#define SEG 4
#define NB 256          // sort buckets
#define ILV 4           // face-subset waves per tile block
#define REC_STRIDE 24   // floats per face record (unsorted staging)
#define INITKEY 0x7f800000FFFFFFFFull

__device__ inline unsigned fkey(float f) {
  unsigned u = __float_as_uint(f);
  return (u & 0x80000000u) ? ~u : (u | 0x80000000u);
}
__device__ inline float unfkey(unsigned k) {
  return (k & 0x80000000u) ? __uint_as_float(k & 0x7fffffffu) : __uint_as_float(~k);
}

// ---------------- transform: v_pix = [Kx/z, Ky/z, z] ----------------
__global__ void k_transform(const float* __restrict__ verts, const float* __restrict__ Km,
                            const float* __restrict__ Rt, float* __restrict__ vpix,
                            int B, int V) {
  int i = blockIdx.x * blockDim.x + threadIdx.x;
  if (i >= B * V) return;
  int b = i / V;
  float x = verts[(size_t)i * 3 + 0], y = verts[(size_t)i * 3 + 1], z = verts[(size_t)i * 3 + 2];
  const float* R = Rt + (size_t)b * 12;
  float cx = __fadd_rn(__fadd_rn(__fadd_rn(__fmul_rn(R[0], x), __fmul_rn(R[1], y)), __fmul_rn(R[2], z)), R[3]);
  float cy = __fadd_rn(__fadd_rn(__fadd_rn(__fmul_rn(R[4], x), __fmul_rn(R[5], y)), __fmul_rn(R[6], z)), R[7]);
  float cz = __fadd_rn(__fadd_rn(__fadd_rn(__fmul_rn(R[8], x), __fmul_rn(R[9], y)), __fmul_rn(R[10], z)), R[11]);
  const float* Kb = Km + (size_t)b * 9;
  float px = __fadd_rn(__fadd_rn(__fmul_rn(Kb[0], cx), __fmul_rn(Kb[1], cy)), __fmul_rn(Kb[2], cz));
  float py = __fadd_rn(__fadd_rn(__fmul_rn(Kb[3], cx), __fmul_rn(Kb[4], cy)), __fmul_rn(Kb[5], cz));
  vpix[(size_t)i * 3 + 0] = __fdiv_rn(px, cz);
  vpix[(size_t)i * 3 + 1] = __fdiv_rn(py, cz);
  vpix[(size_t)i * 3 + 2] = cz;
}

// ---------------- init workspace ----------------
__global__ void k_init(unsigned long long* __restrict__ keys, int nkeys,
                       int* __restrict__ hist, int* __restrict__ cursor, int nbkt,
                       unsigned* __restrict__ minmax) {
  int i = blockIdx.x * blockDim.x + threadIdx.x;
  if (keys && i < nkeys) keys[i] = INITKEY;  // (inf, -1)
  if (i < nbkt) { hist[i] = 0; cursor[i] = 0; }
  if (i == 0 && minmax) { minmax[0] = 0xFFFFFFFFu; minmax[1] = 0u; }
}

// ---------------- per-face precompute (unsorted staging) ----------------
// rec: ax,ay,bx,by,cx,cy, e0x,e0y,e1x,e1y,e2x,e2y, za,zb,zc, sprime, ar,
//      minx,maxx,miny,maxy, zmin, pad*2
__global__ void k_faceprep(const float* __restrict__ vpix, const int* __restrict__ vi,
                           float* __restrict__ rec, unsigned* __restrict__ minmax,
                           int B, int V, int F) {
  int i = blockIdx.x * blockDim.x + threadIdx.x;
  if (i >= B * F) return;
  int b = i / F, f = i - b * F;
  int i0 = vi[f * 3 + 0], i1 = vi[f * 3 + 1], i2 = vi[f * 3 + 2];
  const float* base = vpix + (size_t)b * V * 3;
  float ax = base[(size_t)i0 * 3], ay = base[(size_t)i0 * 3 + 1], az = base[(size_t)i0 * 3 + 2];
  float bx = base[(size_t)i1 * 3], by = base[(size_t)i1 * 3 + 1], bz = base[(size_t)i1 * 3 + 2];
  float cx = base[(size_t)i2 * 3], cy = base[(size_t)i2 * 3 + 1], cz = base[(size_t)i2 * 3 + 2];
  float e0x = __fsub_rn(cx, bx), e0y = __fsub_rn(cy, by);
  float e1x = __fsub_rn(ax, cx), e1y = __fsub_rn(ay, cy);
  float e2x = __fsub_rn(bx, ax), e2y = __fsub_rn(by, ay);
  float area = __fsub_rn(__fmul_rn(e2x, __fsub_rn(cy, ay)), __fmul_rn(e2y, __fsub_rn(cx, ax)));
  float s = (area > 0.f) ? 1.f : ((area < 0.f) ? -1.f : 0.f);
  bool nz = fabsf(area) > 1e-8f;
  bool zv = (az > 0.f) && (bz > 0.f) && (cz > 0.f);
  float sprime = (nz && zv) ? s : __uint_as_float(0x7fc00000u);  // NaN fails all >=0 tests
  float ar = nz ? area : 1.0f;
  float zmin = fminf(az, fminf(bz, cz));
  float* r = rec + (size_t)i * REC_STRIDE;
  r[0] = ax; r[1] = ay; r[2] = bx; r[3] = by; r[4] = cx; r[5] = cy;
  r[6] = e0x; r[7] = e0y; r[8] = e1x; r[9] = e1y; r[10] = e2x; r[11] = e2y;
  r[12] = az; r[13] = bz; r[14] = cz; r[15] = sprime; r[16] = ar;
  r[17] = fminf(ax, fminf(bx, cx));
  r[18] = fmaxf(ax, fmaxf(bx, cx));
  r[19] = fminf(ay, fminf(by, cy));
  r[20] = fmaxf(ay, fmaxf(by, cy));
  r[21] = zmin; r[22] = 0.f; r[23] = 0.f;
  if (minmax && zmin == zmin) {  // not NaN
    unsigned k = fkey(zmin);
    atomicMin(&minmax[0], k);
    atomicMax(&minmax[1], k);
  }
}

// ---------------- counting sort by zmin ----------------
__global__ void k_hist(const float* __restrict__ rec, const unsigned* __restrict__ minmax,
                       int* __restrict__ hist, int B, int F) {
  int i = blockIdx.x * blockDim.x + threadIdx.x;
  if (i >= B * F) return;
  int b = i / F;
  float zmin = rec[(size_t)i * REC_STRIDE + 21];
  float zlo = unfkey(minmax[0]), zhi = unfkey(minmax[1]);
  float scale = (float)NB / fmaxf(zhi - zlo, 1e-12f);
  int bkt = 0;
  if (zmin == zmin) bkt = min(NB - 1, max(0, (int)((zmin - zlo) * scale)));
  atomicAdd(&hist[b * NB + bkt], 1);
}

__global__ void k_scan(const int* __restrict__ hist, int* __restrict__ boff, int B) {
  __shared__ int sh[NB];
  int t = threadIdx.x;
  for (int b = 0; b < B; ++b) {
    sh[t] = hist[b * NB + t];
    __syncthreads();
    int self = sh[t];
    for (int ofs = 1; ofs < NB; ofs <<= 1) {
      int u = (t >= ofs) ? sh[t - ofs] : 0;
      __syncthreads();
      sh[t] += u;
      __syncthreads();
    }
    boff[b * NB + t] = sh[t] - self;  // exclusive
    __syncthreads();
  }
}

// scatter into zmin-sorted SoA with sp pre-folded into edges (IEEE-exact for sp=+-1/NaN)
// sM = (bucket_floor, zmin, fid_bits, 0)
__global__ void k_scatter(const float* __restrict__ rec, const unsigned* __restrict__ minmax,
                          const int* __restrict__ boff, int* __restrict__ cursor,
                          float4* __restrict__ sA, float4* __restrict__ sB4,
                          float4* __restrict__ sC, float4* __restrict__ sZ1,
                          float4* __restrict__ sbb, float4* __restrict__ sM,
                          int B, int F) {
  int i = blockIdx.x * blockDim.x + threadIdx.x;
  if (i >= B * F) return;
  int b = i / F, f = i - b * F;
  const float* r = rec + (size_t)i * REC_STRIDE;
  float zmin = r[21];
  float zlo = unfkey(minmax[0]), zhi = unfkey(minmax[1]);
  float rng = fmaxf(zhi - zlo, 1e-12f);
  float scale = (float)NB / rng;
  int bkt = 0;
  if (zmin == zmin) bkt = min(NB - 1, max(0, (int)((zmin - zlo) * scale)));
  float floorval = zlo + (float)bkt * (rng / (float)NB);
  int pos = boff[b * NB + bkt] + atomicAdd(&cursor[b * NB + bkt], 1);
  size_t gp = (size_t)b * F + pos;
  float sp = r[15];
  sM[gp]  = make_float4(floorval, zmin, __int_as_float(f), 0.f);
  sbb[gp] = make_float4(r[17], r[18], r[19], r[20]);  // minx,maxx,miny,maxy
  sA[gp]  = make_float4(r[0], r[1], r[2], r[3]);      // ax,ay,bx,by
  sB4[gp] = make_float4(r[4], r[5], __fmul_rn(sp, r[6]), __fmul_rn(sp, r[7]));   // cx,cy,E0x,E0y
  sC[gp]  = make_float4(__fmul_rn(sp, r[8]), __fmul_rn(sp, r[9]),
                        __fmul_rn(sp, r[10]), __fmul_rn(sp, r[11]));             // E1,E2
  sZ1[gp] = make_float4(r[12], r[13], r[14], __fmul_rn(sp, r[16]));              // za,zb,zc,|ar|
}

// ---------------- tile rasterizer: 64 px/block-row, ILV face-subset waves, LDS
// exchange, per-iter zfloor break, divide-skip, software-pipelined prefetch ----
__global__ __launch_bounds__(64 * ILV) void k_raster_tile(const float4* __restrict__ sA,
                                                          const float4* __restrict__ sB4,
                                                          const float4* __restrict__ sC,
                                                          const float4* __restrict__ sZ1,
                                                          const float4* __restrict__ sbb,
                                                          const float4* __restrict__ sM,
                                                          float* __restrict__ o_idx,
                                                          int B, int F) {
  int seg = blockIdx.x;            // x-segment of 64 pixels
  int y   = blockIdx.y;
  int b   = blockIdx.z;
  int tid = threadIdx.x;
  int w = tid >> 6, lane = tid & 63;
  __shared__ unsigned long long sk[64];
  if (tid < 64) sk[tid] = INITKEY;
  __syncthreads();
  size_t fb = (size_t)b * F;
  float px = seg * 64 + lane + 0.5f, py = y + 0.5f;
  float wx0 = seg * 64 + 0.5f, wx1 = wx0 + 63.0f;
  unsigned long long bestkey = INITKEY;
  float bestz = INFINITY;
  int pos = w;
  // prime the pipeline (pos = w < ILV <= F for any realistic F)
  float4 M  = sM[fb + pos];
  float4 bb = sbb[fb + pos];
  float4 a0 = sA[fb + pos];
  float4 a1 = sB4[fb + pos];
  float4 a2 = sC[fb + pos];
  int it = 0;
  while (pos < F) {
    int nxt = pos + ILV;
    int nl = (nxt < F) ? nxt : (F - 1);
    // unconditional prefetch of next position (wave-uniform broadcast, L2-resident)
    float4 Mn  = sM[fb + nl];
    float4 bbn = sbb[fb + nl];
    float4 a0n = sA[fb + nl];
    float4 a1n = sB4[fb + nl];
    float4 a2n = sC[fb + nl];
    // early break: bucket floor lower-bounds zmin of this and all later faces
    float floor0 = __fmul_rn(M.x, 0.9999f) - 1e-5f;  // margin: never skips a tie
    if (__all(floor0 > bestz)) break;
    ++it;
    if ((it & 7) == 0) {  // periodic cross-wave exchange via LDS
      unsigned long long old = atomicMin(&sk[lane], bestkey);
      if (old < bestkey) { bestkey = old; bestz = __uint_as_float((unsigned)(bestkey >> 32)); }
    }
    bool cull = (py < bb.z) || (py > bb.w) || (bb.y < wx0) || (bb.x > wx1);
    if (!cull) {
      // t_i == w_i * sp bit-exactly (sp pre-folded; -0>=0 true, NaN false)
      float t0 = __fsub_rn(__fmul_rn(a1.z, __fsub_rn(py, a0.w)), __fmul_rn(a1.w, __fsub_rn(px, a0.z)));
      float t1 = __fsub_rn(__fmul_rn(a2.x, __fsub_rn(py, a1.y)), __fmul_rn(a2.y, __fsub_rn(px, a1.x)));
      float t2 = __fsub_rn(__fmul_rn(a2.z, __fsub_rn(py, a0.y)), __fmul_rn(a2.w, __fsub_rn(px, a0.x)));
      bool inside = (t0 >= 0.f) && (t1 >= 0.f) && (t2 >= 0.f);
      // divide-skip: face with zmin*0.9999 > bestz provably can't beat or tie
      if (inside && !(__fmul_rn(M.y, 0.9999f) > bestz)) {
        float4 zz = sZ1[fb + pos];   // za,zb,zc,|ar| — only load on the rare path
        float u0 = __fdiv_rn(__fdiv_rn(t0, zz.w), zz.x);
        float u1 = __fdiv_rn(__fdiv_rn(t1, zz.w), zz.y);
        float u2 = __fdiv_rn(__fdiv_rn(t2, zz.w), zz.z);
        float invz = __fadd_rn(__fadd_rn(u0, u1), u2);
        if (invz > 0.f) {
          float z = __fdiv_rn(1.0f, fmaxf(invz, 1e-12f));
          int fid = __float_as_int(M.z);
          unsigned long long ck = ((unsigned long long)__float_as_uint(z) << 32) | (unsigned)fid;
          if (ck < bestkey) {
            bestkey = ck;
            bestz = z;
            atomicMin(&sk[lane], ck);  // push so other waves see it at their next exchange
          }
        }
      }
    }
    pos = nxt;
    M = Mn; bb = bbn; a0 = a0n; a1 = a1n; a2 = a2n;
  }
  atomicMin(&sk[lane], bestkey);
  __syncthreads();
  if (tid < 64) {
    unsigned long long k = sk[tid];
    unsigned zb = (unsigned)(k >> 32);
    o_idx[(size_t)b * (H_ * W_) + (size_t)y * W_ + seg * 64 + tid] =
        (zb >= 0x7f800000u) ? -1.0f : (float)(int)(unsigned)(k & 0xffffffffu);
  }
}

// ---------------- fallback rasterizer (unsorted, global keys) ----------------
__global__ __launch_bounds__(256) void k_raster(const float* __restrict__ rec,
                                                unsigned long long* __restrict__ keys,
                                                int B, int F) {
  int x = threadIdx.x;
  int y = blockIdx.x;
  int b = blockIdx.y;
  int seg = blockIdx.z;
  int f0 = (int)((long long)seg * F / SEG);
  int f1 = (int)((long long)(seg + 1) * F / SEG);
  float px = x + 0.5f, py = y + 0.5f;
  float bestz = INFINITY; int besti = -1;
  const float* rb = rec + (size_t)b * F * REC_STRIDE;
  for (int f = f0; f < f1; ++f) {
    const float* r = rb + (size_t)f * REC_STRIDE;
    float miny = r[19], maxy = r[20], minx = r[17], maxx = r[18];
    if (py < miny || py > maxy || maxx < 0.5f || minx > (float)W_ - 0.5f) continue;
    float e0x = r[6], e0y = r[7], e1x = r[8], e1y = r[9], e2x = r[10], e2y = r[11];
    float za = r[12], zb = r[13], zc = r[14], sp = r[15], ar = r[16];
    float w0 = __fsub_rn(__fmul_rn(e0x, __fsub_rn(py, r[3])), __fmul_rn(e0y, __fsub_rn(px, r[2])));
    float w1 = __fsub_rn(__fmul_rn(e1x, __fsub_rn(py, r[5])), __fmul_rn(e1y, __fsub_rn(px, r[4])));
    float w2 = __fsub_rn(__fmul_rn(e2x, __fsub_rn(py, r[1])), __fmul_rn(e2y, __fsub_rn(px, r[0])));
    bool inside = (__fmul_rn(w0, sp) >= 0.f) && (__fmul_rn(w1, sp) >= 0.f) && (__fmul_rn(w2, sp) >= 0.f);
    if (inside) {
      float t0 = __fdiv_rn(__fdiv_rn(w0, ar), za);
      float t1 = __fdiv_rn(__fdiv_rn(w1, ar), zb);
      float t2 = __fdiv_rn(__fdiv_rn(w2, ar), zc);
      float invz = __fadd_rn(__fadd_rn(t0, t1), t2);
      if (invz > 0.f) {
        float z = __fdiv_rn(1.0f, fmaxf(invz, 1e-12f));
        if (z < bestz) { bestz = z; besti = f; }
      }
    }
  }
  if (besti >= 0) {
    unsigned long long key = ((unsigned long long)__float_as_uint(bestz) << 32) | (unsigned)besti;
    atomicMin(&keys[(size_t)b * (H_ * W_) + y * W_ + x], key);
  }
}

__global__ void k_resolve(const unsigned long long* __restrict__ keys, float* __restrict__ idxout, int n) {
  int i = blockIdx.x * blockDim.x + threadIdx.x;
  if (i >= n) return;
  unsigned long long k = keys[i];
  unsigned zb = (unsigned)(k >> 32);
  idxout[i] = (zb >= 0x7f800000u) ? -1.0f : (float)(int)(unsigned)(k & 0xffffffffu);
}

// ---------------- last-resort rasterizer (no workspace) ----------------
__global__ void k_raster_direct(const float* __restrict__ vpix, const int* __restrict__ vi,
                                float* __restrict__ idxout, int B, int V, int F) {
  int p = blockIdx.x * blockDim.x + threadIdx.x;
  if (p >= B * H_ * W_) return;
  int b = p / (H_ * W_); int pid = p - b * (H_ * W_);
  float px = (pid & (W_ - 1)) + 0.5f, py = (pid >> 8) + 0.5f;
  const float* base = vpix + (size_t)b * V * 3;
  float bestz = INFINITY; int besti = -1;
  for (int f = 0; f < F; ++f) {
    int i0 = vi[f * 3], i1 = vi[f * 3 + 1], i2 = vi[f * 3 + 2];
    float ax = base[(size_t)i0 * 3], ay = base[(size_t)i0 * 3 + 1], za = base[(size_t)i0 * 3 + 2];
    float bx = base[(size_t)i1 * 3], by = base[(size_t)i1 * 3 + 1], zb = base[(size_t)i1 * 3 + 2];
    float cx = base[(size_t)i2 * 3], cy = base[(size_t)i2 * 3 + 1], zc = base[(size_t)i2 * 3 + 2];
    float e0x = __fsub_rn(cx, bx), e0y = __fsub_rn(cy, by);
    float e1x = __fsub_rn(ax, cx), e1y = __fsub_rn(ay, cy);
    float e2x = __fsub_rn(bx, ax), e2y = __fsub_rn(by, ay);
    float area = __fsub_rn(__fmul_rn(e2x, __fsub_rn(cy, ay)), __fmul_rn(e2y, __fsub_rn(cx, ax)));
    float s = (area > 0.f) ? 1.f : ((area < 0.f) ? -1.f : 0.f);
    bool nz = fabsf(area) > 1e-8f;
    bool zv = (za > 0.f) && (zb > 0.f) && (zc > 0.f);
    float sp = (nz && zv) ? s : __uint_as_float(0x7fc00000u);
    float ar = nz ? area : 1.0f;
    float w0 = __fsub_rn(__fmul_rn(e0x, __fsub_rn(py, by)), __fmul_rn(e0y, __fsub_rn(px, bx)));
    float w1 = __fsub_rn(__fmul_rn(e1x, __fsub_rn(py, cy)), __fmul_rn(e1y, __fsub_rn(px, cx)));
    float w2 = __fsub_rn(__fmul_rn(e2x, __fsub_rn(py, ay)), __fmul_rn(e2y, __fsub_rn(px, ax)));
    bool inside = (__fmul_rn(w0, sp) >= 0.f) && (__fmul_rn(w1, sp) >= 0.f) && (__fmul_rn(w2, sp) >= 0.f);
    if (inside) {
      float invz = __fadd_rn(__fadd_rn(__fdiv_rn(__fdiv_rn(w0, ar), za),
                                       __fdiv_rn(__fdiv_rn(w1, ar), zb)),
                             __fdiv_rn(__fdiv_rn(w2, ar), zc));
      if (invz > 0.f) {
        float z = __fdiv_rn(1.0f, fmaxf(invz, 1e-12f));
        if (z < bestz) { bestz = z; besti = f; }
      }
    }
  }
  idxout[p] = (float)besti;
}

// ---------------- render + interpolate + grid_sample, fused ----------------
__global__ __launch_bounds__(256) void k_render(const float* __restrict__ vpix, const int* __restrict__ vi,
                                                const int* __restrict__ vti, const float* __restrict__ vt,
                                                const float* __restrict__ tex, const float* __restrict__ idxin,
                                                float* __restrict__ o_img, float* __restrict__ o_depth,
                                                float* __restrict__ o_vt, float* __restrict__ o_bary,
                                                float* __restrict__ o_mask,
                                                int B, int V, int F, int TH, int TW) {
  int p = blockIdx.x * blockDim.x + threadIdx.x;
  if (p >= B * H_ * W_) return;
  int HW = H_ * W_;
  int b = p / HW; int pid = p - b * HW;
  int y = pid >> 8, x = pid & (W_ - 1);
  int idx = (int)idxin[p];
  size_t pix2 = (size_t)b * 2 * HW + pid;
  size_t pix3 = (size_t)b * 3 * HW + pid;
  if (idx < 0) {
    o_depth[p] = 0.f; o_mask[p] = 0.f;
    o_vt[pix2] = 0.f; o_vt[pix2 + HW] = 0.f;
    o_bary[pix3] = 0.f; o_bary[pix3 + HW] = 0.f; o_bary[pix3 + 2 * HW] = 0.f;
    o_img[pix3] = 0.f; o_img[pix3 + HW] = 0.f; o_img[pix3 + 2 * HW] = 0.f;
    return;
  }
  const float* base = vpix + (size_t)b * V * 3;
  int i0 = vi[idx * 3], i1 = vi[idx * 3 + 1], i2 = vi[idx * 3 + 2];
  float ax = base[(size_t)i0 * 3], ay = base[(size_t)i0 * 3 + 1], az = base[(size_t)i0 * 3 + 2];
  float bx = base[(size_t)i1 * 3], by = base[(size_t)i1 * 3 + 1], bz = base[(size_t)i1 * 3 + 2];
  float cx = base[(size_t)i2 * 3], cy = base[(size_t)i2 * 3 + 1], cz = base[(size_t)i2 * 3 + 2];
  float ptx = x + 0.5f, pty = y + 0.5f;
  float w0 = __fsub_rn(__fmul_rn(__fsub_rn(cx, bx), __fsub_rn(pty, by)),
                       __fmul_rn(__fsub_rn(cy, by), __fsub_rn(ptx, bx)));
  float w1 = __fsub_rn(__fmul_rn(__fsub_rn(ax, cx), __fsub_rn(pty, cy)),
                       __fmul_rn(__fsub_rn(ay, cy), __fsub_rn(ptx, cx)));
  float w2 = __fsub_rn(__fmul_rn(__fsub_rn(bx, ax), __fsub_rn(pty, ay)),
                       __fmul_rn(__fsub_rn(by, ay), __fsub_rn(ptx, ax)));
  float area = __fadd_rn(__fadd_rn(w0, w1), w2);
  float ar = (fabsf(area) > 1e-8f) ? area : 1.0f;
  float f0 = __fdiv_rn(__fdiv_rn(w0, ar), fmaxf(az, 1e-8f));
  float f1 = __fdiv_rn(__fdiv_rn(w1, ar), fmaxf(bz, 1e-8f));
  float f2 = __fdiv_rn(__fdiv_rn(w2, ar), fmaxf(cz, 1e-8f));
  float invz = __fadd_rn(__fadd_rn(f0, f1), f2);
  float invz_s = (fabsf(invz) > 1e-12f) ? invz : 1.0f;
  float depth = __fdiv_rn(1.0f, invz_s);
  float bary0 = __fdiv_rn(f0, invz_s);
  float bary1 = __fdiv_rn(f1, invz_s);
  float bary2 = __fdiv_rn(f2, invz_s);
  o_depth[p] = depth; o_mask[p] = 1.0f;
  o_bary[pix3] = bary0; o_bary[pix3 + HW] = bary1; o_bary[pix3 + 2 * HW] = bary2;
  int t0 = vti[idx * 3], t1 = vti[idx * 3 + 1], t2 = vti[idx * 3 + 2];
  float u0x = __fsub_rn(__fmul_rn(vt[(size_t)t0 * 2], 2.f), 1.f);
  float u0y = __fsub_rn(__fmul_rn(vt[(size_t)t0 * 2 + 1], 2.f), 1.f);
  float u1x = __fsub_rn(__fmul_rn(vt[(size_t)t1 * 2], 2.f), 1.f);
  float u1y = __fsub_rn(__fmul_rn(vt[(size_t)t1 * 2 + 1], 2.f), 1.f);
  float u2x = __fsub_rn(__fmul_rn(vt[(size_t)t2 * 2], 2.f), 1.f);
  float u2y = __fsub_rn(__fmul_rn(vt[(size_t)t2 * 2 + 1], 2.f), 1.f);
  float gx = __fadd_rn(__fadd_rn(__fmul_rn(u0x, bary0), __fmul_rn(u1x, bary1)), __fmul_rn(u2x, bary2));
  float gy = __fadd_rn(__fadd_rn(__fmul_rn(u0y, bary0), __fmul_rn(u1y, bary1)), __fmul_rn(u2y, bary2));
  o_vt[pix2] = gx; o_vt[pix2 + HW] = gy;
  float sx = __fsub_rn(__fdiv_rn(__fmul_rn(__fadd_rn(gx, 1.0f), (float)TW), 2.0f), 0.5f);
  float sy = __fsub_rn(__fdiv_rn(__fmul_rn(__fadd_rn(gy, 1.0f), (float)TH), 2.0f), 0.5f);
  float x0f = floorf(sx), y0f = floorf(sy);
  float wx = __fsub_rn(sx, x0f), wy = __fsub_rn(sy, y0f);
  float omx = __fsub_rn(1.0f, wx), omy = __fsub_rn(1.0f, wy);
  int x0 = (int)x0f, y0 = (int)y0f;
  int x1 = x0 + 1, y1 = y0 + 1;
  bool v00 = (x0 >= 0) && (x0 < TW) && (y0 >= 0) && (y0 < TH);
  bool v10 = (x1 >= 0) && (x1 < TW) && (y0 >= 0) && (y0 < TH);
  bool v01 = (x0 >= 0) && (x0 < TW) && (y1 >= 0) && (y1 < TH);
  bool v11 = (x1 >= 0) && (x1 < TW) && (y1 >= 0) && (y1 < TH);
  int x0c = min(max(x0, 0), TW - 1), x1c = min(max(x1, 0), TW - 1);
  int y0c = min(max(y0, 0), TH - 1), y1c = min(max(y1, 0), TH - 1);
  const float* tb = tex + (size_t)b * 3 * TH * TW;
  #pragma unroll
  for (int ch = 0; ch < 3; ++ch) {
    const float* tc = tb + (size_t)ch * TH * TW;
    float g00 = v00 ? tc[(size_t)y0c * TW + x0c] : 0.f;
    float g10 = v10 ? tc[(size_t)y0c * TW + x1c] : 0.f;
    float g01 = v01 ? tc[(size_t)y1c * TW + x0c] : 0.f;
    float g11 = v11 ? tc[(size_t)y1c * TW + x1c] : 0.f;
    float r = __fmul_rn(__fmul_rn(g00, omx), omy);
    r = __fadd_rn(r, __fmul_rn(__fmul_rn(g10, wx), omy));
    r = __fadd_rn(r, __fmul_rn(__fmul_rn(g01, omx), wy));
    r = __fadd_rn(r, __fmul_rn(__fmul_rn(g11, wx), wy));
    o_img[pix3 + (size_t)ch * HW] = r;
  }
}

extern "C" void kernel_launch(void* const* d_in, const int* in_sizes, int n_in,
                              void* d_out, int out_size, void* d_ws, size_t ws_size,
                              hipStream_t stream) {
  const float* verts = (const float*)d_in[0];
  const float* tex   = (const float*)d_in[1];
  const float* Km    = (const float*)d_in[2];
  const float* Rt    = (const float*)d_in[3];
  const float* vt    = (const float*)d_in[4];
  const int*   vi    = (const int*)d_in[5];
  const int*   vti   = (const int*)d_in[6];

  int B = in_sizes[2] / 9;
  int V = in_sizes[0] / (3 * B);
  int F = in_sizes[5] / 3;
  long texhw = (long)in_sizes[1] / (B * 3);
  int TH = (int)(sqrt((double)texhw) + 0.5);
  int TW = TH;
  const int HW = H_ * W_;

  float* out = (float*)d_out;
  float* o_img   = out;
  float* o_depth = o_img + (size_t)B * 3 * HW;
  float* o_vpix  = o_depth + (size_t)B * HW;
  float* o_vt    = o_vpix + (size_t)B * V * 3;
  float* o_idx   = o_vt + (size_t)B * 2 * HW;
  float* o_bary  = o_idx + (size_t)B * HW;
  float* o_mask  = o_bary + (size_t)B * 3 * HW;

  k_transform<<<(B * V + 255) / 256, 256, 0, stream>>>(verts, Km, Rt, o_vpix, B, V);

  size_t f4Bytes   = (size_t)B * F * 16;
  size_t recBytes  = (size_t)B * F * REC_STRIDE * 4;
  size_t histBytes = (size_t)B * NB * 4;
  size_t keysBytes = (size_t)B * HW * 8;
  size_t needSorted = 6 * f4Bytes + recBytes + 3 * histBytes + 16;
  size_t needBasic  = keysBytes + recBytes;

  if (ws_size >= needSorted) {
    char* w = (char*)d_ws;   // 16B-aligned arrays first
    float4* sA  = (float4*)w;  w += f4Bytes;
    float4* sB4 = (float4*)w;  w += f4Bytes;
    float4* sC  = (float4*)w;  w += f4Bytes;
    float4* sZ1 = (float4*)w;  w += f4Bytes;
    float4* sbb = (float4*)w;  w += f4Bytes;
    float4* sM  = (float4*)w;  w += f4Bytes;
    float*  rec = (float*)w;   w += recBytes;
    int*    hist = (int*)w;    w += histBytes;
    int*    boff = (int*)w;    w += histBytes;
    int*    cursor = (int*)w;  w += histBytes;
    unsigned* minmax = (unsigned*)w;

    k_init<<<(B * NB + 255) / 256, 256, 0, stream>>>((unsigned long long*)nullptr, 0, hist, cursor, B * NB, minmax);
    k_faceprep<<<(B * F + 255) / 256, 256, 0, stream>>>(o_vpix, vi, rec, minmax, B, V, F);
    k_hist<<<(B * F + 255) / 256, 256, 0, stream>>>(rec, minmax, hist, B, F);
    k_scan<<<1, NB, 0, stream>>>(hist, boff, B);
    k_scatter<<<(B * F + 255) / 256, 256, 0, stream>>>(rec, minmax, boff, cursor,
                                                       sA, sB4, sC, sZ1, sbb, sM, B, F);
    dim3 rg(W_ / 64, H_, B);
    k_raster_tile<<<rg, 64 * ILV, 0, stream>>>(sA, sB4, sC, sZ1, sbb, sM, o_idx, B, F);
  } else if (ws_size >= needBasic) {
    unsigned long long* keys = (unsigned long long*)d_ws;
    float* rec = (float*)((char*)d_ws + keysBytes);
    k_init<<<(B * HW + 255) / 256, 256, 0, stream>>>(keys, B * HW, (int*)nullptr, (int*)nullptr, 0, (unsigned*)nullptr);
    k_faceprep<<<(B * F + 255) / 256, 256, 0, stream>>>(o_vpix, vi, rec, (unsigned*)nullptr, B, V, F);
    dim3 rg(H_, B, SEG);
    k_raster<<<rg, 256, 0, stream>>>(rec, keys, B, F);
    k_resolve<<<(B * HW + 255) / 256, 256, 0, stream>>>(keys, o_idx, B * HW);
  } else {
    k_raster_direct<<<(B * HW + 255) / 256, 256, 0, stream>>>(o_vpix, vi, o_idx, B, V, F);
  }

  k_render<<<(B * HW + 255) / 256, 256, 0, stream>>>(o_vpix, vi, vti, vt, tex, o_idx,
                                                     o_img, o_depth, o_vt, o_bary, o_mask,
                                                     B, V, F, TH, TW);
}

// Round 6
// 415.687 us; speedup vs baseline: 1.3750x; 1.3750x over previous
//
#include <hip/hip_runtime.h>
#include <cmath>

#define H_ 256
#define W_ 256
#define SEG 4
#define NB 256          // zmin sort buckets
#define NBAND (H_ / 4)  // 64 y-bands of 4 rows
#define ILV 4           // face-subset waves per tile block
#define REC_STRIDE 24   // floats per face record (unsorted staging)
#define INITKEY 0x7f800000FFFFFFFFull

__device__ inline unsigned fkey(float f) {
  unsigned u = __float_as_uint(f);
  return (u & 0x80000000u) ? ~u : (u | 0x80000000u);
}
__device__ inline float unfkey(unsigned k) {
  return (k & 0x80000000u) ? __uint_as_float(k & 0x7fffffffu) : __uint_as_float(~k);
}

// zmin -> bucket (must be the ONLY way buckets are computed; deterministic IEEE ops)
__device__ inline int zbucket(float zmin, float zlo, float scale) {
  int bkt = 0;
  if (zmin == zmin) bkt = min(NB - 1, max(0, (int)((zmin - zlo) * scale)));
  return bkt;
}

// integer pixel bbox from float bbox; returns false if face can never win a pixel.
// Conservative-exact at pixel centers (px = x+0.5): y<ylo  <=>  py<miny etc.
__device__ inline bool face_bbox_int(const float* __restrict__ r,
                                     int& xlo, int& xhi, int& ylo, int& yhi) {
  float sp = r[15];
  if (!(sp == sp)) return false;  // invalid face: reference gives z=inf, never selected
  float minx = r[17], maxx = r[18], miny = r[19], maxy = r[20];
  int xl = (int)ceilf(fmaxf(fminf(minx - 0.5f, 1e9f), -1e9f));
  int xh = (int)floorf(fmaxf(fminf(maxx - 0.5f, 1e9f), -1e9f));
  int yl = (int)ceilf(fmaxf(fminf(miny - 0.5f, 1e9f), -1e9f));
  int yh = (int)floorf(fmaxf(fminf(maxy - 0.5f, 1e9f), -1e9f));
  if (xl > xh || yl > yh) return false;
  if (xh < 0 || xl > W_ - 1 || yh < 0 || yl > H_ - 1) return false;
  xlo = max(xl, 0); xhi = min(xh, W_ - 1);
  ylo = max(yl, 0); yhi = min(yh, H_ - 1);
  return true;
}

// ---------------- transform: v_pix = [Kx/z, Ky/z, z] ----------------
__global__ void k_transform(const float* __restrict__ verts, const float* __restrict__ Km,
                            const float* __restrict__ Rt, float* __restrict__ vpix,
                            int B, int V) {
  int i = blockIdx.x * blockDim.x + threadIdx.x;
  if (i >= B * V) return;
  int b = i / V;
  float x = verts[(size_t)i * 3 + 0], y = verts[(size_t)i * 3 + 1], z = verts[(size_t)i * 3 + 2];
  const float* R = Rt + (size_t)b * 12;
  float cx = __fadd_rn(__fadd_rn(__fadd_rn(__fmul_rn(R[0], x), __fmul_rn(R[1], y)), __fmul_rn(R[2], z)), R[3]);
  float cy = __fadd_rn(__fadd_rn(__fadd_rn(__fmul_rn(R[4], x), __fmul_rn(R[5], y)), __fmul_rn(R[6], z)), R[7]);
  float cz = __fadd_rn(__fadd_rn(__fadd_rn(__fmul_rn(R[8], x), __fmul_rn(R[9], y)), __fmul_rn(R[10], z)), R[11]);
  const float* Kb = Km + (size_t)b * 9;
  float px = __fadd_rn(__fadd_rn(__fmul_rn(Kb[0], cx), __fmul_rn(Kb[1], cy)), __fmul_rn(Kb[2], cz));
  float py = __fadd_rn(__fadd_rn(__fmul_rn(Kb[3], cx), __fmul_rn(Kb[4], cy)), __fmul_rn(Kb[5], cz));
  vpix[(size_t)i * 3 + 0] = __fdiv_rn(px, cz);
  vpix[(size_t)i * 3 + 1] = __fdiv_rn(py, cz);
  vpix[(size_t)i * 3 + 2] = cz;
}

// ---------------- init workspace ----------------
__global__ void k_init(unsigned long long* __restrict__ keys, int nkeys,
                       int* __restrict__ hist, int* __restrict__ cursor, int nbkt,
                       int* __restrict__ cnt, int* __restrict__ bcur, int nband,
                       unsigned* __restrict__ minmax) {
  int i = blockIdx.x * blockDim.x + threadIdx.x;
  if (keys && i < nkeys) keys[i] = INITKEY;
  if (hist && i < nbkt) { hist[i] = 0; cursor[i] = 0; }
  if (cnt && i < nband) { cnt[i] = 0; bcur[i] = 0; }
  if (i == 0 && minmax) { minmax[0] = 0xFFFFFFFFu; minmax[1] = 0u; }
}

// ---------------- per-face precompute (unsorted staging) ----------------
__global__ void k_faceprep(const float* __restrict__ vpix, const int* __restrict__ vi,
                           float* __restrict__ rec, unsigned* __restrict__ minmax,
                           int B, int V, int F) {
  int i = blockIdx.x * blockDim.x + threadIdx.x;
  if (i >= B * F) return;
  int b = i / F, f = i - b * F;
  int i0 = vi[f * 3 + 0], i1 = vi[f * 3 + 1], i2 = vi[f * 3 + 2];
  const float* base = vpix + (size_t)b * V * 3;
  float ax = base[(size_t)i0 * 3], ay = base[(size_t)i0 * 3 + 1], az = base[(size_t)i0 * 3 + 2];
  float bx = base[(size_t)i1 * 3], by = base[(size_t)i1 * 3 + 1], bz = base[(size_t)i1 * 3 + 2];
  float cx = base[(size_t)i2 * 3], cy = base[(size_t)i2 * 3 + 1], cz = base[(size_t)i2 * 3 + 2];
  float e0x = __fsub_rn(cx, bx), e0y = __fsub_rn(cy, by);
  float e1x = __fsub_rn(ax, cx), e1y = __fsub_rn(ay, cy);
  float e2x = __fsub_rn(bx, ax), e2y = __fsub_rn(by, ay);
  float area = __fsub_rn(__fmul_rn(e2x, __fsub_rn(cy, ay)), __fmul_rn(e2y, __fsub_rn(cx, ax)));
  float s = (area > 0.f) ? 1.f : ((area < 0.f) ? -1.f : 0.f);
  bool nz = fabsf(area) > 1e-8f;
  bool zv = (az > 0.f) && (bz > 0.f) && (cz > 0.f);
  float sprime = (nz && zv) ? s : __uint_as_float(0x7fc00000u);
  float ar = nz ? area : 1.0f;
  float zmin = fminf(az, fminf(bz, cz));
  float* r = rec + (size_t)i * REC_STRIDE;
  r[0] = ax; r[1] = ay; r[2] = bx; r[3] = by; r[4] = cx; r[5] = cy;
  r[6] = e0x; r[7] = e0y; r[8] = e1x; r[9] = e1y; r[10] = e2x; r[11] = e2y;
  r[12] = az; r[13] = bz; r[14] = cz; r[15] = sprime; r[16] = ar;
  r[17] = fminf(ax, fminf(bx, cx));
  r[18] = fmaxf(ax, fmaxf(bx, cx));
  r[19] = fminf(ay, fminf(by, cy));
  r[20] = fmaxf(ay, fmaxf(by, cy));
  r[21] = zmin; r[22] = 0.f; r[23] = 0.f;
  if (minmax && zmin == zmin) {
    unsigned k = fkey(zmin);
    atomicMin(&minmax[0], k);
    atomicMax(&minmax[1], k);
  }
}

// ---------------- counting: global zmin-buckets + per-(band,bucket) ----------------
__global__ void k_hist(const float* __restrict__ rec, const unsigned* __restrict__ minmax,
                       int* __restrict__ hist, int* __restrict__ cnt, int B, int F) {
  int i = blockIdx.x * blockDim.x + threadIdx.x;
  if (i >= B * F) return;
  int b = i / F;
  const float* r = rec + (size_t)i * REC_STRIDE;
  float zmin = r[21];
  float zlo = unfkey(minmax[0]), zhi = unfkey(minmax[1]);
  float scale = (float)NB / fmaxf(zhi - zlo, 1e-12f);
  int bkt = zbucket(zmin, zlo, scale);
  atomicAdd(&hist[b * NB + bkt], 1);
  if (cnt) {
    int xlo, xhi, ylo, yhi;
    if (face_bbox_int(r, xlo, xhi, ylo, yhi)) {
      for (int band = (ylo >> 2); band <= (yhi >> 2); ++band)
        atomicAdd(&cnt[(b * NBAND + band) * NB + bkt], 1);
    }
  }
}

__global__ void k_scan(const int* __restrict__ hist, int* __restrict__ boff, int B) {
  __shared__ int sh[NB];
  int t = threadIdx.x;
  for (int b = 0; b < B; ++b) {
    sh[t] = hist[b * NB + t];
    __syncthreads();
    int self = sh[t];
    for (int ofs = 1; ofs < NB; ofs <<= 1) {
      int u = (t >= ofs) ? sh[t - ofs] : 0;
      __syncthreads();
      sh[t] += u;
      __syncthreads();
    }
    boff[b * NB + t] = sh[t] - self;
    __syncthreads();
  }
}

// per-(band) exclusive prefix over buckets; bstart[row][NB] = total length
__global__ void k_bandscan(const int* __restrict__ cnt, int* __restrict__ bstart) {
  __shared__ int sh[NB];
  int rowi = blockIdx.x;
  int t = threadIdx.x;
  sh[t] = cnt[rowi * NB + t];
  __syncthreads();
  int self = sh[t];
  for (int ofs = 1; ofs < NB; ofs <<= 1) {
    int u = (t >= ofs) ? sh[t - ofs] : 0;
    __syncthreads();
    sh[t] += u;
    __syncthreads();
  }
  bstart[rowi * (NB + 1) + t] = sh[t] - self;
  if (t == NB - 1) bstart[rowi * (NB + 1) + NB] = sh[t];
}

// scatter into zmin-sorted SoA (sp pre-folded, IEEE-exact) + fill band lists
// entry: {bbox u8x4, pos|fid<<16, zmin, zfloor}
__global__ void k_scatter(const float* __restrict__ rec, const unsigned* __restrict__ minmax,
                          const int* __restrict__ boff, int* __restrict__ cursor,
                          float4* __restrict__ sA, float4* __restrict__ sB4,
                          float4* __restrict__ sC, float4* __restrict__ sZ1,
                          float4* __restrict__ sbb, float4* __restrict__ sM,
                          const int* __restrict__ bstart, int* __restrict__ bcur,
                          uint4* __restrict__ list, int B, int F) {
  int i = blockIdx.x * blockDim.x + threadIdx.x;
  if (i >= B * F) return;
  int b = i / F, f = i - b * F;
  const float* r = rec + (size_t)i * REC_STRIDE;
  float zmin = r[21];
  float zlo = unfkey(minmax[0]), zhi = unfkey(minmax[1]);
  float rng = fmaxf(zhi - zlo, 1e-12f);
  float scale = (float)NB / rng;
  int bkt = zbucket(zmin, zlo, scale);
  float floorval = zlo + (float)bkt * (rng / (float)NB);
  int pos = boff[b * NB + bkt] + atomicAdd(&cursor[b * NB + bkt], 1);
  size_t gp = (size_t)b * F + pos;
  float sp = r[15];
  sM[gp]  = make_float4(floorval, zmin, __int_as_float(f), 0.f);
  sbb[gp] = make_float4(r[17], r[18], r[19], r[20]);
  sA[gp]  = make_float4(r[0], r[1], r[2], r[3]);
  sB4[gp] = make_float4(r[4], r[5], __fmul_rn(sp, r[6]), __fmul_rn(sp, r[7]));
  sC[gp]  = make_float4(__fmul_rn(sp, r[8]), __fmul_rn(sp, r[9]),
                        __fmul_rn(sp, r[10]), __fmul_rn(sp, r[11]));
  sZ1[gp] = make_float4(r[12], r[13], r[14], __fmul_rn(sp, r[16]));
  if (list) {
    int xlo, xhi, ylo, yhi;
    if (face_bbox_int(r, xlo, xhi, ylo, yhi)) {
      uint4 ent = make_uint4((unsigned)xlo | ((unsigned)xhi << 8) | ((unsigned)ylo << 16) | ((unsigned)yhi << 24),
                             (unsigned)pos | ((unsigned)f << 16),
                             __float_as_uint(zmin), __float_as_uint(floorval));
      for (int band = (ylo >> 2); band <= (yhi >> 2); ++band) {
        int rowi = b * NBAND + band;
        int slot = bstart[rowi * (NB + 1) + bkt] + atomicAdd(&bcur[rowi * NB + bkt], 1);
        list[(size_t)rowi * F + slot] = ent;
      }
    }
  }
}

// ---------------- band rasterizer: 64 px/block-row, ILV waves, LDS exchange,
// bucket-floor break, divide-skip, cull-gated record loads ----------------
__global__ __launch_bounds__(64 * ILV) void k_raster_band(const uint4* __restrict__ list,
                                                          const int* __restrict__ bstart,
                                                          const float4* __restrict__ sA,
                                                          const float4* __restrict__ sB4,
                                                          const float4* __restrict__ sC,
                                                          const float4* __restrict__ sZ1,
                                                          float* __restrict__ o_idx,
                                                          int B, int F) {
  int seg = blockIdx.x;
  int y   = blockIdx.y;
  int b   = blockIdx.z;
  int tid = threadIdx.x;
  int w = tid >> 6, lane = tid & 63;
  __shared__ unsigned long long sk[64];
  if (tid < 64) sk[tid] = INITKEY;
  __syncthreads();
  int rowi = b * NBAND + (y >> 2);
  int len = bstart[rowi * (NB + 1) + NB];
  const uint4* L = list + (size_t)rowi * F;
  size_t fb = (size_t)b * F;
  float px = seg * 64 + lane + 0.5f, py = y + 0.5f;
  int sx0 = seg * 64, sx1 = sx0 + 63;
  unsigned long long bestkey = INITKEY;
  float bestz = INFINITY;
  int it = 0;
  int pos = w;
  uint4 e = (pos < len) ? L[pos] : make_uint4(0u, 0u, 0u, 0x7f800000u);
  while (pos < len) {
    int nxt = pos + ILV;
    uint4 en = L[(nxt < len) ? nxt : (len - 1)];  // entry needed unconditionally -> prefetch safe
    // break: stored bucket floor lower-bounds zmin of this and all later entries
    float floor0 = __fmul_rn(__uint_as_float(e.w), 0.9999f) - 1e-5f;  // margin: never skips a tie
    if (__all(floor0 > bestz)) break;
    ++it;
    if ((it & 7) == 0) {  // periodic cross-wave exchange via LDS
      unsigned long long old = atomicMin(&sk[lane], bestkey);
      if (old < bestkey) { bestkey = old; bestz = __uint_as_float((unsigned)(bestkey >> 32)); }
    }
    int xlo = (int)(e.x & 255u), xhi = (int)((e.x >> 8) & 255u);
    int ylo = (int)((e.x >> 16) & 255u), yhi = (int)(e.x >> 24);
    bool cull = (y < ylo) || (y > yhi) || (xhi < sx0) || (xlo > sx1);
    if (!cull) {
      int p = (int)(e.y & 0xffffu);
      float4 a0 = sA[fb + p];
      float4 a1 = sB4[fb + p];
      float4 a2 = sC[fb + p];
      // t_i == w_i * sp bit-exactly (sp pre-folded; -0>=0 true, NaN false)
      float t0 = __fsub_rn(__fmul_rn(a1.z, __fsub_rn(py, a0.w)), __fmul_rn(a1.w, __fsub_rn(px, a0.z)));
      float t1 = __fsub_rn(__fmul_rn(a2.x, __fsub_rn(py, a1.y)), __fmul_rn(a2.y, __fsub_rn(px, a1.x)));
      float t2 = __fsub_rn(__fmul_rn(a2.z, __fsub_rn(py, a0.y)), __fmul_rn(a2.w, __fsub_rn(px, a0.x)));
      bool inside = (t0 >= 0.f) && (t1 >= 0.f) && (t2 >= 0.f);
      // divide-skip: face with zmin*0.9999 > bestz provably can't beat or tie
      if (inside && !(__fmul_rn(__uint_as_float(e.z), 0.9999f) > bestz)) {
        float4 zz = sZ1[fb + p];
        float u0 = __fdiv_rn(__fdiv_rn(t0, zz.w), zz.x);
        float u1 = __fdiv_rn(__fdiv_rn(t1, zz.w), zz.y);
        float u2 = __fdiv_rn(__fdiv_rn(t2, zz.w), zz.z);
        float invz = __fadd_rn(__fadd_rn(u0, u1), u2);
        if (invz > 0.f) {
          float z = __fdiv_rn(1.0f, fmaxf(invz, 1e-12f));
          unsigned fid = e.y >> 16;
          unsigned long long ck = ((unsigned long long)__float_as_uint(z) << 32) | fid;
          if (ck < bestkey) {
            bestkey = ck; bestz = z;
            atomicMin(&sk[lane], ck);
          }
        }
      }
    }
    pos = nxt;
    e = en;
  }
  atomicMin(&sk[lane], bestkey);
  __syncthreads();
  if (tid < 64) {
    unsigned long long k = sk[tid];
    unsigned zb = (unsigned)(k >> 32);
    o_idx[(size_t)b * (H_ * W_) + (size_t)y * W_ + seg * 64 + tid] =
        (zb >= 0x7f800000u) ? -1.0f : (float)(int)(unsigned)(k & 0xffffffffu);
  }
}

// ---------------- R3-structure fallback (zmin-sorted, no banding) ----------------
__global__ __launch_bounds__(64 * ILV) void k_raster_tile(const float4* __restrict__ sA,
                                                          const float4* __restrict__ sB4,
                                                          const float4* __restrict__ sC,
                                                          const float4* __restrict__ sZ1,
                                                          const float4* __restrict__ sbb,
                                                          const float4* __restrict__ sM,
                                                          float* __restrict__ o_idx,
                                                          int B, int F) {
  int seg = blockIdx.x;
  int y   = blockIdx.y;
  int b   = blockIdx.z;
  int tid = threadIdx.x;
  int w = tid >> 6, lane = tid & 63;
  __shared__ unsigned long long sk[64];
  if (tid < 64) sk[tid] = INITKEY;
  __syncthreads();
  size_t fb = (size_t)b * F;
  float px = seg * 64 + lane + 0.5f, py = y + 0.5f;
  float wx0 = seg * 64 + 0.5f, wx1 = wx0 + 63.0f;
  unsigned long long bestkey = INITKEY;
  float bestz = INFINITY;
  int it = 0;
  int pos = w;
  float4 M  = sM[fb + pos];
  float4 bb = sbb[fb + pos];
  while (pos < F) {
    int nxt = pos + ILV;
    int nl = (nxt < F) ? nxt : (F - 1);
    float4 Mn  = sM[fb + nl];
    float4 bbn = sbb[fb + nl];
    float floor0 = __fmul_rn(M.x, 0.9999f) - 1e-5f;
    if (__all(floor0 > bestz)) break;
    ++it;
    if ((it & 7) == 0) {
      unsigned long long old = atomicMin(&sk[lane], bestkey);
      if (old < bestkey) { bestkey = old; bestz = __uint_as_float((unsigned)(bestkey >> 32)); }
    }
    bool cull = (py < bb.z) || (py > bb.w) || (bb.y < wx0) || (bb.x > wx1);
    if (!cull) {
      float4 a0 = sA[fb + pos];
      float4 a1 = sB4[fb + pos];
      float4 a2 = sC[fb + pos];
      float t0 = __fsub_rn(__fmul_rn(a1.z, __fsub_rn(py, a0.w)), __fmul_rn(a1.w, __fsub_rn(px, a0.z)));
      float t1 = __fsub_rn(__fmul_rn(a2.x, __fsub_rn(py, a1.y)), __fmul_rn(a2.y, __fsub_rn(px, a1.x)));
      float t2 = __fsub_rn(__fmul_rn(a2.z, __fsub_rn(py, a0.y)), __fmul_rn(a2.w, __fsub_rn(px, a0.x)));
      bool inside = (t0 >= 0.f) && (t1 >= 0.f) && (t2 >= 0.f);
      if (inside && !(__fmul_rn(M.y, 0.9999f) > bestz)) {
        float4 zz = sZ1[fb + pos];
        float u0 = __fdiv_rn(__fdiv_rn(t0, zz.w), zz.x);
        float u1 = __fdiv_rn(__fdiv_rn(t1, zz.w), zz.y);
        float u2 = __fdiv_rn(__fdiv_rn(t2, zz.w), zz.z);
        float invz = __fadd_rn(__fadd_rn(u0, u1), u2);
        if (invz > 0.f) {
          float z = __fdiv_rn(1.0f, fmaxf(invz, 1e-12f));
          int fid = __float_as_int(M.z);
          unsigned long long ck = ((unsigned long long)__float_as_uint(z) << 32) | (unsigned)fid;
          if (ck < bestkey) { bestkey = ck; bestz = z; atomicMin(&sk[lane], ck); }
        }
      }
    }
    pos = nxt;
    M = Mn; bb = bbn;
  }
  atomicMin(&sk[lane], bestkey);
  __syncthreads();
  if (tid < 64) {
    unsigned long long k = sk[tid];
    unsigned zb = (unsigned)(k >> 32);
    o_idx[(size_t)b * (H_ * W_) + (size_t)y * W_ + seg * 64 + tid] =
        (zb >= 0x7f800000u) ? -1.0f : (float)(int)(unsigned)(k & 0xffffffffu);
  }
}

// ---------------- last-resort rasterizer (no workspace) ----------------
__global__ void k_raster_direct(const float* __restrict__ vpix, const int* __restrict__ vi,
                                float* __restrict__ idxout, int B, int V, int F) {
  int p = blockIdx.x * blockDim.x + threadIdx.x;
  if (p >= B * H_ * W_) return;
  int b = p / (H_ * W_); int pid = p - b * (H_ * W_);
  float px = (pid & (W_ - 1)) + 0.5f, py = (pid >> 8) + 0.5f;
  const float* base = vpix + (size_t)b * V * 3;
  float bestz = INFINITY; int besti = -1;
  for (int f = 0; f < F; ++f) {
    int i0 = vi[f * 3], i1 = vi[f * 3 + 1], i2 = vi[f * 3 + 2];
    float ax = base[(size_t)i0 * 3], ay = base[(size_t)i0 * 3 + 1], za = base[(size_t)i0 * 3 + 2];
    float bx = base[(size_t)i1 * 3], by = base[(size_t)i1 * 3 + 1], zb = base[(size_t)i1 * 3 + 2];
    float cx = base[(size_t)i2 * 3], cy = base[(size_t)i2 * 3 + 1], zc = base[(size_t)i2 * 3 + 2];
    float e0x = __fsub_rn(cx, bx), e0y = __fsub_rn(cy, by);
    float e1x = __fsub_rn(ax, cx), e1y = __fsub_rn(ay, cy);
    float e2x = __fsub_rn(bx, ax), e2y = __fsub_rn(by, ay);
    float area = __fsub_rn(__fmul_rn(e2x, __fsub_rn(cy, ay)), __fmul_rn(e2y, __fsub_rn(cx, ax)));
    float s = (area > 0.f) ? 1.f : ((area < 0.f) ? -1.f : 0.f);
    bool nz = fabsf(area) > 1e-8f;
    bool zv = (za > 0.f) && (zb > 0.f) && (zc > 0.f);
    float sp = (nz && zv) ? s : __uint_as_float(0x7fc00000u);
    float ar = nz ? area : 1.0f;
    float w0 = __fsub_rn(__fmul_rn(e0x, __fsub_rn(py, by)), __fmul_rn(e0y, __fsub_rn(px, bx)));
    float w1 = __fsub_rn(__fmul_rn(e1x, __fsub_rn(py, cy)), __fmul_rn(e1y, __fsub_rn(px, cx)));
    float w2 = __fsub_rn(__fmul_rn(e2x, __fsub_rn(py, ay)), __fmul_rn(e2y, __fsub_rn(px, ax)));
    bool inside = (__fmul_rn(w0, sp) >= 0.f) && (__fmul_rn(w1, sp) >= 0.f) && (__fmul_rn(w2, sp) >= 0.f);
    if (inside) {
      float invz = __fadd_rn(__fadd_rn(__fdiv_rn(__fdiv_rn(w0, ar), za),
                                       __fdiv_rn(__fdiv_rn(w1, ar), zb)),
                             __fdiv_rn(__fdiv_rn(w2, ar), zc));
      if (invz > 0.f) {
        float z = __fdiv_rn(1.0f, fmaxf(invz, 1e-12f));
        if (z < bestz) { bestz = z; besti = f; }
      }
    }
  }
  idxout[p] = (float)besti;
}

// ---------------- render + interpolate + grid_sample, fused ----------------
__global__ __launch_bounds__(256) void k_render(const float* __restrict__ vpix, const int* __restrict__ vi,
                                                const int* __restrict__ vti, const float* __restrict__ vt,
                                                const float* __restrict__ tex, const float* __restrict__ idxin,
                                                float* __restrict__ o_img, float* __restrict__ o_depth,
                                                float* __restrict__ o_vt, float* __restrict__ o_bary,
                                                float* __restrict__ o_mask,
                                                int B, int V, int F, int TH, int TW) {
  int p = blockIdx.x * blockDim.x + threadIdx.x;
  if (p >= B * H_ * W_) return;
  int HW = H_ * W_;
  int b = p / HW; int pid = p - b * HW;
  int y = pid >> 8, x = pid & (W_ - 1);
  int idx = (int)idxin[p];
  size_t pix2 = (size_t)b * 2 * HW + pid;
  size_t pix3 = (size_t)b * 3 * HW + pid;
  if (idx < 0) {
    o_depth[p] = 0.f; o_mask[p] = 0.f;
    o_vt[pix2] = 0.f; o_vt[pix2 + HW] = 0.f;
    o_bary[pix3] = 0.f; o_bary[pix3 + HW] = 0.f; o_bary[pix3 + 2 * HW] = 0.f;
    o_img[pix3] = 0.f; o_img[pix3 + HW] = 0.f; o_img[pix3 + 2 * HW] = 0.f;
    return;
  }
  const float* base = vpix + (size_t)b * V * 3;
  int i0 = vi[idx * 3], i1 = vi[idx * 3 + 1], i2 = vi[idx * 3 + 2];
  float ax = base[(size_t)i0 * 3], ay = base[(size_t)i0 * 3 + 1], az = base[(size_t)i0 * 3 + 2];
  float bx = base[(size_t)i1 * 3], by = base[(size_t)i1 * 3 + 1], bz = base[(size_t)i1 * 3 + 2];
  float cx = base[(size_t)i2 * 3], cy = base[(size_t)i2 * 3 + 1], cz = base[(size_t)i2 * 3 + 2];
  float ptx = x + 0.5f, pty = y + 0.5f;
  float w0 = __fsub_rn(__fmul_rn(__fsub_rn(cx, bx), __fsub_rn(pty, by)),
                       __fmul_rn(__fsub_rn(cy, by), __fsub_rn(ptx, bx)));
  float w1 = __fsub_rn(__fmul_rn(__fsub_rn(ax, cx), __fsub_rn(pty, cy)),
                       __fmul_rn(__fsub_rn(ay, cy), __fsub_rn(ptx, cx)));
  float w2 = __fsub_rn(__fmul_rn(__fsub_rn(bx, ax), __fsub_rn(pty, ay)),
                       __fmul_rn(__fsub_rn(by, ay), __fsub_rn(ptx, ax)));
  float area = __fadd_rn(__fadd_rn(w0, w1), w2);
  float ar = (fabsf(area) > 1e-8f) ? area : 1.0f;
  float f0 = __fdiv_rn(__fdiv_rn(w0, ar), fmaxf(az, 1e-8f));
  float f1 = __fdiv_rn(__fdiv_rn(w1, ar), fmaxf(bz, 1e-8f));
  float f2 = __fdiv_rn(__fdiv_rn(w2, ar), fmaxf(cz, 1e-8f));
  float invz = __fadd_rn(__fadd_rn(f0, f1), f2);
  float invz_s = (fabsf(invz) > 1e-12f) ? invz : 1.0f;
  float depth = __fdiv_rn(1.0f, invz_s);
  float bary0 = __fdiv_rn(f0, invz_s);
  float bary1 = __fdiv_rn(f1, invz_s);
  float bary2 = __fdiv_rn(f2, invz_s);
  o_depth[p] = depth; o_mask[p] = 1.0f;
  o_bary[pix3] = bary0; o_bary[pix3 + HW] = bary1; o_bary[pix3 + 2 * HW] = bary2;
  int t0 = vti[idx * 3], t1 = vti[idx * 3 + 1], t2 = vti[idx * 3 + 2];
  float u0x = __fsub_rn(__fmul_rn(vt[(size_t)t0 * 2], 2.f), 1.f);
  float u0y = __fsub_rn(__fmul_rn(vt[(size_t)t0 * 2 + 1], 2.f), 1.f);
  float u1x = __fsub_rn(__fmul_rn(vt[(size_t)t1 * 2], 2.f), 1.f);
  float u1y = __fsub_rn(__fmul_rn(vt[(size_t)t1 * 2 + 1], 2.f), 1.f);
  float u2x = __fsub_rn(__fmul_rn(vt[(size_t)t2 * 2], 2.f), 1.f);
  float u2y = __fsub_rn(__fmul_rn(vt[(size_t)t2 * 2 + 1], 2.f), 1.f);
  float gx = __fadd_rn(__fadd_rn(__fmul_rn(u0x, bary0), __fmul_rn(u1x, bary1)), __fmul_rn(u2x, bary2));
  float gy = __fadd_rn(__fadd_rn(__fmul_rn(u0y, bary0), __fmul_rn(u1y, bary1)), __fmul_rn(u2y, bary2));
  o_vt[pix2] = gx; o_vt[pix2 + HW] = gy;
  float sx = __fsub_rn(__fdiv_rn(__fmul_rn(__fadd_rn(gx, 1.0f), (float)TW), 2.0f), 0.5f);
  float sy = __fsub_rn(__fdiv_rn(__fmul_rn(__fadd_rn(gy, 1.0f), (float)TH), 2.0f), 0.5f);
  float x0f = floorf(sx), y0f = floorf(sy);
  float wx = __fsub_rn(sx, x0f), wy = __fsub_rn(sy, y0f);
  float omx = __fsub_rn(1.0f, wx), omy = __fsub_rn(1.0f, wy);
  int x0 = (int)x0f, y0 = (int)y0f;
  int x1 = x0 + 1, y1 = y0 + 1;
  bool v00 = (x0 >= 0) && (x0 < TW) && (y0 >= 0) && (y0 < TH);
  bool v10 = (x1 >= 0) && (x1 < TW) && (y0 >= 0) && (y0 < TH);
  bool v01 = (x0 >= 0) && (x0 < TW) && (y1 >= 0) && (y1 < TH);
  bool v11 = (x1 >= 0) && (x1 < TW) && (y1 >= 0) && (y1 < TH);
  int x0c = min(max(x0, 0), TW - 1), x1c = min(max(x1, 0), TW - 1);
  int y0c = min(max(y0, 0), TH - 1), y1c = min(max(y1, 0), TH - 1);
  const float* tb = tex + (size_t)b * 3 * TH * TW;
  #pragma unroll
  for (int ch = 0; ch < 3; ++ch) {
    const float* tc = tb + (size_t)ch * TH * TW;
    float g00 = v00 ? tc[(size_t)y0c * TW + x0c] : 0.f;
    float g10 = v10 ? tc[(size_t)y0c * TW + x1c] : 0.f;
    float g01 = v01 ? tc[(size_t)y1c * TW + x0c] : 0.f;
    float g11 = v11 ? tc[(size_t)y1c * TW + x1c] : 0.f;
    float r = __fmul_rn(__fmul_rn(g00, omx), omy);
    r = __fadd_rn(r, __fmul_rn(__fmul_rn(g10, wx), omy));
    r = __fadd_rn(r, __fmul_rn(__fmul_rn(g01, omx), wy));
    r = __fadd_rn(r, __fmul_rn(__fmul_rn(g11, wx), wy));
    o_img[pix3 + (size_t)ch * HW] = r;
  }
}

extern "C" void kernel_launch(void* const* d_in, const int* in_sizes, int n_in,
                              void* d_out, int out_size, void* d_ws, size_t ws_size,
                              hipStream_t stream) {
  const float* verts = (const float*)d_in[0];
  const float* tex   = (const float*)d_in[1];
  const float* Km    = (const float*)d_in[2];
  const float* Rt    = (const float*)d_in[3];
  const float* vt    = (const float*)d_in[4];
  const int*   vi    = (const int*)d_in[5];
  const int*   vti   = (const int*)d_in[6];

  int B = in_sizes[2] / 9;
  int V = in_sizes[0] / (3 * B);
  int F = in_sizes[5] / 3;
  long texhw = (long)in_sizes[1] / (B * 3);
  int TH = (int)(sqrt((double)texhw) + 0.5);
  int TW = TH;
  const int HW = H_ * W_;

  float* out = (float*)d_out;
  float* o_img   = out;
  float* o_depth = o_img + (size_t)B * 3 * HW;
  float* o_vpix  = o_depth + (size_t)B * HW;
  float* o_vt    = o_vpix + (size_t)B * V * 3;
  float* o_idx   = o_vt + (size_t)B * 2 * HW;
  float* o_bary  = o_idx + (size_t)B * HW;
  float* o_mask  = o_bary + (size_t)B * 3 * HW;

  k_transform<<<(B * V + 255) / 256, 256, 0, stream>>>(verts, Km, Rt, o_vpix, B, V);

  size_t f4Bytes    = (size_t)B * F * 16;
  size_t recBytes   = (size_t)B * F * REC_STRIDE * 4;
  size_t histBytes  = (size_t)B * NB * 4;
  size_t listBytes  = (size_t)B * NBAND * F * 16;
  size_t cntBytes   = (size_t)B * NBAND * NB * 4;
  size_t bstBytes   = (size_t)B * NBAND * (NB + 1) * 4;
  size_t keysBytes  = (size_t)B * HW * 8;
  size_t needBinned = 6 * f4Bytes + listBytes + recBytes + 3 * histBytes +
                      2 * cntBytes + bstBytes + 64;
  size_t needSorted = 6 * f4Bytes + recBytes + 3 * histBytes + 16;
  size_t needBasic  = keysBytes + recBytes;

  if (ws_size >= needSorted) {
    bool binned = (ws_size >= needBinned) && (F <= 65535);
    char* w = (char*)d_ws;   // 16B-aligned arrays first
    float4* sA  = (float4*)w;  w += f4Bytes;
    float4* sB4 = (float4*)w;  w += f4Bytes;
    float4* sC  = (float4*)w;  w += f4Bytes;
    float4* sZ1 = (float4*)w;  w += f4Bytes;
    float4* sbb = (float4*)w;  w += f4Bytes;
    float4* sM  = (float4*)w;  w += f4Bytes;
    uint4*  list = nullptr;
    if (binned) { list = (uint4*)w; w += listBytes; }
    float*  rec = (float*)w;   w += recBytes;
    int*    hist = (int*)w;    w += histBytes;
    int*    boff = (int*)w;    w += histBytes;
    int*    cursor = (int*)w;  w += histBytes;
    int *cnt = nullptr, *bstart = nullptr, *bcur = nullptr;
    if (binned) {
      cnt = (int*)w;    w += cntBytes;
      bcur = (int*)w;   w += cntBytes;
      bstart = (int*)w; w += bstBytes;
    }
    unsigned* minmax = (unsigned*)w;

    int ninit = binned ? (B * NBAND * NB) : (B * NB);
    k_init<<<(ninit + 255) / 256, 256, 0, stream>>>((unsigned long long*)nullptr, 0,
                                                    hist, cursor, B * NB,
                                                    cnt, bcur, binned ? B * NBAND * NB : 0, minmax);
    k_faceprep<<<(B * F + 255) / 256, 256, 0, stream>>>(o_vpix, vi, rec, minmax, B, V, F);
    k_hist<<<(B * F + 255) / 256, 256, 0, stream>>>(rec, minmax, hist, cnt, B, F);
    k_scan<<<1, NB, 0, stream>>>(hist, boff, B);
    if (binned) k_bandscan<<<B * NBAND, NB, 0, stream>>>(cnt, bstart);
    k_scatter<<<(B * F + 255) / 256, 256, 0, stream>>>(rec, minmax, boff, cursor,
                                                       sA, sB4, sC, sZ1, sbb, sM,
                                                       bstart, bcur, list, B, F);
    dim3 rg(W_ / 64, H_, B);
    if (binned)
      k_raster_band<<<rg, 64 * ILV, 0, stream>>>(list, bstart, sA, sB4, sC, sZ1, o_idx, B, F);
    else
      k_raster_tile<<<rg, 64 * ILV, 0, stream>>>(sA, sB4, sC, sZ1, sbb, sM, o_idx, B, F);
  } else {
    k_raster_direct<<<(B * HW + 255) / 256, 256, 0, stream>>>(o_vpix, vi, o_idx, B, V, F);
  }

  k_render<<<(B * HW + 255) / 256, 256, 0, stream>>>(o_vpix, vi, vti, vt, tex, o_idx,
                                                     o_img, o_depth, o_vt, o_bary, o_mask,
                                                     B, V, F, TH, TW);
}

// Round 7
// 412.934 us; speedup vs baseline: 1.3842x; 1.0067x over previous
//
#include <hip/hip_runtime.h>
#include <cmath>

#define H_ 256
#define W_ 256
#define NB 256           // zmin sort buckets
#define BANDSH 4         // log2(band height): 16-row bands
#define NBAND (H_ >> BANDSH)
#define ILV 4            // face-subset waves per tile block
#define REC_STRIDE 24    // floats per face record (unsorted staging)
#define INITKEY 0x7f800000FFFFFFFFull

__device__ inline unsigned fkey(float f) {
  unsigned u = __float_as_uint(f);
  return (u & 0x80000000u) ? ~u : (u | 0x80000000u);
}
__device__ inline float unfkey(unsigned k) {
  return (k & 0x80000000u) ? __uint_as_float(k & 0x7fffffffu) : __uint_as_float(~k);
}

__device__ inline int zbucket(float zmin, float zlo, float scale) {
  int bkt = 0;
  if (zmin == zmin) bkt = min(NB - 1, max(0, (int)((zmin - zlo) * scale)));
  return bkt;
}

// integer pixel bbox from float bbox; false if face can never win a pixel.
__device__ inline bool face_bbox_int(const float* __restrict__ r,
                                     int& xlo, int& xhi, int& ylo, int& yhi) {
  float sp = r[15];
  if (!(sp == sp)) return false;  // invalid face: reference z=inf, never selected
  float minx = r[17], maxx = r[18], miny = r[19], maxy = r[20];
  int xl = (int)ceilf(fmaxf(fminf(minx - 0.5f, 1e9f), -1e9f));
  int xh = (int)floorf(fmaxf(fminf(maxx - 0.5f, 1e9f), -1e9f));
  int yl = (int)ceilf(fmaxf(fminf(miny - 0.5f, 1e9f), -1e9f));
  int yh = (int)floorf(fmaxf(fminf(maxy - 0.5f, 1e9f), -1e9f));
  if (xl > xh || yl > yh) return false;
  if (xh < 0 || xl > W_ - 1 || yh < 0 || yl > H_ - 1) return false;
  xlo = max(xl, 0); xhi = min(xh, W_ - 1);
  ylo = max(yl, 0); yhi = min(yh, H_ - 1);
  return true;
}

// ---------------- transform ----------------
__global__ void k_transform(const float* __restrict__ verts, const float* __restrict__ Km,
                            const float* __restrict__ Rt, float* __restrict__ vpix,
                            int B, int V) {
  int i = blockIdx.x * blockDim.x + threadIdx.x;
  if (i >= B * V) return;
  int b = i / V;
  float x = verts[(size_t)i * 3 + 0], y = verts[(size_t)i * 3 + 1], z = verts[(size_t)i * 3 + 2];
  const float* R = Rt + (size_t)b * 12;
  float cx = __fadd_rn(__fadd_rn(__fadd_rn(__fmul_rn(R[0], x), __fmul_rn(R[1], y)), __fmul_rn(R[2], z)), R[3]);
  float cy = __fadd_rn(__fadd_rn(__fadd_rn(__fmul_rn(R[4], x), __fmul_rn(R[5], y)), __fmul_rn(R[6], z)), R[7]);
  float cz = __fadd_rn(__fadd_rn(__fadd_rn(__fmul_rn(R[8], x), __fmul_rn(R[9], y)), __fmul_rn(R[10], z)), R[11]);
  const float* Kb = Km + (size_t)b * 9;
  float px = __fadd_rn(__fadd_rn(__fmul_rn(Kb[0], cx), __fmul_rn(Kb[1], cy)), __fmul_rn(Kb[2], cz));
  float py = __fadd_rn(__fadd_rn(__fmul_rn(Kb[3], cx), __fmul_rn(Kb[4], cy)), __fmul_rn(Kb[5], cz));
  vpix[(size_t)i * 3 + 0] = __fdiv_rn(px, cz);
  vpix[(size_t)i * 3 + 1] = __fdiv_rn(py, cz);
  vpix[(size_t)i * 3 + 2] = cz;
}

// ---------------- init workspace ----------------
__global__ void k_init(int* __restrict__ hist, int* __restrict__ cursor, int nbkt,
                       int* __restrict__ cnt, int* __restrict__ bcur, int nband,
                       unsigned* __restrict__ minmax) {
  int i = blockIdx.x * blockDim.x + threadIdx.x;
  if (hist && i < nbkt) { hist[i] = 0; cursor[i] = 0; }
  if (cnt && i < nband) { cnt[i] = 0; bcur[i] = 0; }
  if (i == 0 && minmax) { minmax[0] = 0xFFFFFFFFu; minmax[1] = 0u; }
}

// ---------------- per-face precompute ----------------
__global__ void k_faceprep(const float* __restrict__ vpix, const int* __restrict__ vi,
                           float* __restrict__ rec, unsigned* __restrict__ minmax,
                           int B, int V, int F) {
  int i = blockIdx.x * blockDim.x + threadIdx.x;
  if (i >= B * F) return;
  int b = i / F, f = i - b * F;
  int i0 = vi[f * 3 + 0], i1 = vi[f * 3 + 1], i2 = vi[f * 3 + 2];
  const float* base = vpix + (size_t)b * V * 3;
  float ax = base[(size_t)i0 * 3], ay = base[(size_t)i0 * 3 + 1], az = base[(size_t)i0 * 3 + 2];
  float bx = base[(size_t)i1 * 3], by = base[(size_t)i1 * 3 + 1], bz = base[(size_t)i1 * 3 + 2];
  float cx = base[(size_t)i2 * 3], cy = base[(size_t)i2 * 3 + 1], cz = base[(size_t)i2 * 3 + 2];
  float e0x = __fsub_rn(cx, bx), e0y = __fsub_rn(cy, by);
  float e1x = __fsub_rn(ax, cx), e1y = __fsub_rn(ay, cy);
  float e2x = __fsub_rn(bx, ax), e2y = __fsub_rn(by, ay);
  float area = __fsub_rn(__fmul_rn(e2x, __fsub_rn(cy, ay)), __fmul_rn(e2y, __fsub_rn(cx, ax)));
  float s = (area > 0.f) ? 1.f : ((area < 0.f) ? -1.f : 0.f);
  bool nz = fabsf(area) > 1e-8f;
  bool zv = (az > 0.f) && (bz > 0.f) && (cz > 0.f);
  float sprime = (nz && zv) ? s : __uint_as_float(0x7fc00000u);
  float ar = nz ? area : 1.0f;
  float zmin = fminf(az, fminf(bz, cz));
  float* r = rec + (size_t)i * REC_STRIDE;
  r[0] = ax; r[1] = ay; r[2] = bx; r[3] = by; r[4] = cx; r[5] = cy;
  r[6] = e0x; r[7] = e0y; r[8] = e1x; r[9] = e1y; r[10] = e2x; r[11] = e2y;
  r[12] = az; r[13] = bz; r[14] = cz; r[15] = sprime; r[16] = ar;
  r[17] = fminf(ax, fminf(bx, cx));
  r[18] = fmaxf(ax, fmaxf(bx, cx));
  r[19] = fminf(ay, fminf(by, cy));
  r[20] = fmaxf(ay, fmaxf(by, cy));
  r[21] = zmin; r[22] = 0.f; r[23] = 0.f;
  if (minmax && zmin == zmin) {
    unsigned k = fkey(zmin);
    atomicMin(&minmax[0], k);
    atomicMax(&minmax[1], k);
  }
}

// ---------------- counting: global zmin-buckets + per-(band,bucket) ----------------
__global__ void k_hist(const float* __restrict__ rec, const unsigned* __restrict__ minmax,
                       int* __restrict__ hist, int* __restrict__ cnt, int B, int F) {
  int i = blockIdx.x * blockDim.x + threadIdx.x;
  if (i >= B * F) return;
  int b = i / F;
  const float* r = rec + (size_t)i * REC_STRIDE;
  float zmin = r[21];
  float zlo = unfkey(minmax[0]), zhi = unfkey(minmax[1]);
  float scale = (float)NB / fmaxf(zhi - zlo, 1e-12f);
  int bkt = zbucket(zmin, zlo, scale);
  atomicAdd(&hist[b * NB + bkt], 1);
  if (cnt) {
    int xlo, xhi, ylo, yhi;
    if (face_bbox_int(r, xlo, xhi, ylo, yhi)) {
      for (int band = (ylo >> BANDSH); band <= (yhi >> BANDSH); ++band)
        atomicAdd(&cnt[(b * NBAND + band) * NB + bkt], 1);
    }
  }
}

__global__ void k_scan(const int* __restrict__ hist, int* __restrict__ boff, int B) {
  __shared__ int sh[NB];
  int t = threadIdx.x;
  for (int b = 0; b < B; ++b) {
    sh[t] = hist[b * NB + t];
    __syncthreads();
    int self = sh[t];
    for (int ofs = 1; ofs < NB; ofs <<= 1) {
      int u = (t >= ofs) ? sh[t - ofs] : 0;
      __syncthreads();
      sh[t] += u;
      __syncthreads();
    }
    boff[b * NB + t] = sh[t] - self;
    __syncthreads();
  }
}

__global__ void k_bandscan(const int* __restrict__ cnt, int* __restrict__ bstart) {
  __shared__ int sh[NB];
  int rowi = blockIdx.x;
  int t = threadIdx.x;
  sh[t] = cnt[rowi * NB + t];
  __syncthreads();
  int self = sh[t];
  for (int ofs = 1; ofs < NB; ofs <<= 1) {
    int u = (t >= ofs) ? sh[t - ofs] : 0;
    __syncthreads();
    sh[t] += u;
    __syncthreads();
  }
  bstart[rowi * (NB + 1) + t] = sh[t] - self;
  if (t == NB - 1) bstart[rowi * (NB + 1) + NB] = sh[t];
}

// scatter into zmin-sorted SoA + band lists with INLINE 64B entries:
// entry = { {bbox u8x4, pos|fid<<16, zmin, zfloor}, a0, a1(sp-folded E0), a2(sp-folded E1/E2) }
__global__ void k_scatter(const float* __restrict__ rec, const unsigned* __restrict__ minmax,
                          const int* __restrict__ boff, int* __restrict__ cursor,
                          float4* __restrict__ sA, float4* __restrict__ sB4,
                          float4* __restrict__ sC, float4* __restrict__ sZ1,
                          float4* __restrict__ sbb, float4* __restrict__ sM,
                          const int* __restrict__ bstart, int* __restrict__ bcur,
                          uint4* __restrict__ list, int B, int F) {
  int i = blockIdx.x * blockDim.x + threadIdx.x;
  if (i >= B * F) return;
  int b = i / F, f = i - b * F;
  const float* r = rec + (size_t)i * REC_STRIDE;
  float zmin = r[21];
  float zlo = unfkey(minmax[0]), zhi = unfkey(minmax[1]);
  float rng = fmaxf(zhi - zlo, 1e-12f);
  float scale = (float)NB / rng;
  int bkt = zbucket(zmin, zlo, scale);
  float floorval = zlo + (float)bkt * (rng / (float)NB);
  int pos = boff[b * NB + bkt] + atomicAdd(&cursor[b * NB + bkt], 1);
  size_t gp = (size_t)b * F + pos;
  float sp = r[15];
  float4 a0 = make_float4(r[0], r[1], r[2], r[3]);
  float4 a1 = make_float4(r[4], r[5], __fmul_rn(sp, r[6]), __fmul_rn(sp, r[7]));
  float4 a2 = make_float4(__fmul_rn(sp, r[8]), __fmul_rn(sp, r[9]),
                          __fmul_rn(sp, r[10]), __fmul_rn(sp, r[11]));
  sM[gp]  = make_float4(floorval, zmin, __int_as_float(f), 0.f);
  sbb[gp] = make_float4(r[17], r[18], r[19], r[20]);
  sA[gp]  = a0;
  sB4[gp] = a1;
  sC[gp]  = a2;
  sZ1[gp] = make_float4(r[12], r[13], r[14], __fmul_rn(sp, r[16]));
  if (list) {
    int xlo, xhi, ylo, yhi;
    if (face_bbox_int(r, xlo, xhi, ylo, yhi)) {
      uint4 meta = make_uint4((unsigned)xlo | ((unsigned)xhi << 8) | ((unsigned)ylo << 16) | ((unsigned)yhi << 24),
                              (unsigned)pos | ((unsigned)f << 16),
                              __float_as_uint(zmin), __float_as_uint(floorval));
      uint4 u1 = make_uint4(__float_as_uint(a0.x), __float_as_uint(a0.y), __float_as_uint(a0.z), __float_as_uint(a0.w));
      uint4 u2 = make_uint4(__float_as_uint(a1.x), __float_as_uint(a1.y), __float_as_uint(a1.z), __float_as_uint(a1.w));
      uint4 u3 = make_uint4(__float_as_uint(a2.x), __float_as_uint(a2.y), __float_as_uint(a2.z), __float_as_uint(a2.w));
      for (int band = (ylo >> BANDSH); band <= (yhi >> BANDSH); ++band) {
        int rowi = b * NBAND + band;
        int slot = bstart[rowi * (NB + 1) + bkt] + atomicAdd(&bcur[rowi * NB + bkt], 1);
        uint4* eb = list + ((size_t)rowi * F + slot) * 4;
        eb[0] = meta; eb[1] = u1; eb[2] = u2; eb[3] = u3;
      }
    }
  }
}

// ---------------- band rasterizer: inline 64B entries, 2-deep pipeline,
// scalar cull, bucket-floor break, divide-skip, LDS exchange ----------------
__global__ __launch_bounds__(64 * ILV) void k_raster_band(const uint4* __restrict__ list,
                                                          const int* __restrict__ bstart,
                                                          const float4* __restrict__ sZ1,
                                                          float* __restrict__ o_idx,
                                                          int B, int F) {
  int seg = blockIdx.x;
  int y   = blockIdx.y;
  int b   = blockIdx.z;
  int tid = threadIdx.x;
  int w = tid >> 6, lane = tid & 63;
  __shared__ unsigned long long sk[64];
  if (tid < 64) sk[tid] = INITKEY;
  __syncthreads();
  int rowi = b * NBAND + (y >> BANDSH);
  int len = bstart[rowi * (NB + 1) + NB];
  const uint4* Lr = list + (size_t)rowi * F * 4;
  size_t fb = (size_t)b * F;
  float px = seg * 64 + lane + 0.5f, py = y + 0.5f;
  int sx0 = seg * 64, sx1 = sx0 + 63;
  unsigned long long bestkey = INITKEY;
  float bestz = INFINITY;
  unsigned long long out;
  if (len <= 0) goto done;
  {
    uint4 A0, A1, A2, A3, B0, B1, B2, B3;
    int pos = w;
    {
      int q0 = (pos < len) ? pos : (len - 1);
      const uint4* e = Lr + (size_t)q0 * 4;
      A0 = e[0]; A1 = e[1]; A2 = e[2]; A3 = e[3];
      int q1 = (pos + ILV < len) ? (pos + ILV) : (len - 1);
      e = Lr + (size_t)q1 * 4;
      B0 = e[0]; B1 = e[1]; B2 = e[2]; B3 = e[3];
    }
    int it = 0;
    while (pos < len) {
      // stage-2 prefetch (sequential, wave-uniform stream)
      int q2 = (pos + 2 * ILV < len) ? (pos + 2 * ILV) : (len - 1);
      const uint4* e2 = Lr + (size_t)q2 * 4;
      uint4 C0 = e2[0], C1 = e2[1], C2 = e2[2], C3 = e2[3];
      // scalarize metadata (wave-uniform)
      unsigned bbox = __builtin_amdgcn_readfirstlane(A0.x);
      unsigned pfid = __builtin_amdgcn_readfirstlane(A0.y);
      float zmn = __uint_as_float(__builtin_amdgcn_readfirstlane(A0.z));
      float zfl = __uint_as_float(__builtin_amdgcn_readfirstlane(A0.w));
      // break: bucket floor lower-bounds zmin of this and all later entries
      float floor0 = __fmul_rn(zfl, 0.9999f) - 1e-5f;  // margin: never skips a tie
      if (__all(floor0 > bestz)) break;
      ++it;
      if ((it & 7) == 0) {  // periodic cross-wave exchange via LDS
        unsigned long long old = atomicMin(&sk[lane], bestkey);
        if (old < bestkey) { bestkey = old; bestz = __uint_as_float((unsigned)(bestkey >> 32)); }
      }
      int xlo = (int)(bbox & 255u), xhi = (int)((bbox >> 8) & 255u);
      int ylo = (int)((bbox >> 16) & 255u), yhi = (int)(bbox >> 24);
      if (!((y < ylo) || (y > yhi) || (xhi < sx0) || (xlo > sx1))) {
        float4 a0 = make_float4(__uint_as_float(A1.x), __uint_as_float(A1.y), __uint_as_float(A1.z), __uint_as_float(A1.w));
        float4 a1 = make_float4(__uint_as_float(A2.x), __uint_as_float(A2.y), __uint_as_float(A2.z), __uint_as_float(A2.w));
        float4 a2 = make_float4(__uint_as_float(A3.x), __uint_as_float(A3.y), __uint_as_float(A3.z), __uint_as_float(A3.w));
        // t_i == w_i * sp bit-exactly (sp pre-folded; -0>=0 true, NaN false)
        float t0 = __fsub_rn(__fmul_rn(a1.z, __fsub_rn(py, a0.w)), __fmul_rn(a1.w, __fsub_rn(px, a0.z)));
        float t1 = __fsub_rn(__fmul_rn(a2.x, __fsub_rn(py, a1.y)), __fmul_rn(a2.y, __fsub_rn(px, a1.x)));
        float t2 = __fsub_rn(__fmul_rn(a2.z, __fsub_rn(py, a0.y)), __fmul_rn(a2.w, __fsub_rn(px, a0.x)));
        bool inside = (t0 >= 0.f) && (t1 >= 0.f) && (t2 >= 0.f);
        // divide-skip: zmin*0.9999 > bestz provably can't beat or tie
        if (inside && !(__fmul_rn(zmn, 0.9999f) > bestz)) {
          int p = (int)(pfid & 0xffffu);
          float4 zz = sZ1[fb + p];   // rare path only
          float u0 = __fdiv_rn(__fdiv_rn(t0, zz.w), zz.x);
          float u1 = __fdiv_rn(__fdiv_rn(t1, zz.w), zz.y);
          float u2 = __fdiv_rn(__fdiv_rn(t2, zz.w), zz.z);
          float invz = __fadd_rn(__fadd_rn(u0, u1), u2);
          if (invz > 0.f) {
            float z = __fdiv_rn(1.0f, fmaxf(invz, 1e-12f));
            unsigned fid = pfid >> 16;
            unsigned long long ck = ((unsigned long long)__float_as_uint(z) << 32) | fid;
            if (ck < bestkey) {
              bestkey = ck; bestz = z;
              atomicMin(&sk[lane], ck);
            }
          }
        }
      }
      pos += ILV;
      A0 = B0; A1 = B1; A2 = B2; A3 = B3;
      B0 = C0; B1 = C1; B2 = C2; B3 = C3;
    }
  }
done:
  atomicMin(&sk[lane], bestkey);
  __syncthreads();
  if (tid < 64) {
    unsigned long long k = sk[tid];
    unsigned zb = (unsigned)(k >> 32);
    o_idx[(size_t)b * (H_ * W_) + (size_t)y * W_ + seg * 64 + tid] =
        (zb >= 0x7f800000u) ? -1.0f : (float)(int)(unsigned)(k & 0xffffffffu);
  }
  (void)out;
}

// ---------------- R3-structure fallback (zmin-sorted, no banding) ----------------
__global__ __launch_bounds__(64 * ILV) void k_raster_tile(const float4* __restrict__ sA,
                                                          const float4* __restrict__ sB4,
                                                          const float4* __restrict__ sC,
                                                          const float4* __restrict__ sZ1,
                                                          const float4* __restrict__ sbb,
                                                          const float4* __restrict__ sM,
                                                          float* __restrict__ o_idx,
                                                          int B, int F) {
  int seg = blockIdx.x;
  int y   = blockIdx.y;
  int b   = blockIdx.z;
  int tid = threadIdx.x;
  int w = tid >> 6, lane = tid & 63;
  __shared__ unsigned long long sk[64];
  if (tid < 64) sk[tid] = INITKEY;
  __syncthreads();
  size_t fb = (size_t)b * F;
  float px = seg * 64 + lane + 0.5f, py = y + 0.5f;
  float wx0 = seg * 64 + 0.5f, wx1 = wx0 + 63.0f;
  unsigned long long bestkey = INITKEY;
  float bestz = INFINITY;
  int it = 0;
  int pos = w;
  float4 M  = sM[fb + pos];
  float4 bb = sbb[fb + pos];
  while (pos < F) {
    int nxt = pos + ILV;
    int nl = (nxt < F) ? nxt : (F - 1);
    float4 Mn  = sM[fb + nl];
    float4 bbn = sbb[fb + nl];
    float floor0 = __fmul_rn(M.x, 0.9999f) - 1e-5f;
    if (__all(floor0 > bestz)) break;
    ++it;
    if ((it & 7) == 0) {
      unsigned long long old = atomicMin(&sk[lane], bestkey);
      if (old < bestkey) { bestkey = old; bestz = __uint_as_float((unsigned)(bestkey >> 32)); }
    }
    bool cull = (py < bb.z) || (py > bb.w) || (bb.y < wx0) || (bb.x > wx1);
    if (!cull) {
      float4 a0 = sA[fb + pos];
      float4 a1 = sB4[fb + pos];
      float4 a2 = sC[fb + pos];
      float t0 = __fsub_rn(__fmul_rn(a1.z, __fsub_rn(py, a0.w)), __fmul_rn(a1.w, __fsub_rn(px, a0.z)));
      float t1 = __fsub_rn(__fmul_rn(a2.x, __fsub_rn(py, a1.y)), __fmul_rn(a2.y, __fsub_rn(px, a1.x)));
      float t2 = __fsub_rn(__fmul_rn(a2.z, __fsub_rn(py, a0.y)), __fmul_rn(a2.w, __fsub_rn(px, a0.x)));
      bool inside = (t0 >= 0.f) && (t1 >= 0.f) && (t2 >= 0.f);
      if (inside && !(__fmul_rn(M.y, 0.9999f) > bestz)) {
        float4 zz = sZ1[fb + pos];
        float u0 = __fdiv_rn(__fdiv_rn(t0, zz.w), zz.x);
        float u1 = __fdiv_rn(__fdiv_rn(t1, zz.w), zz.y);
        float u2 = __fdiv_rn(__fdiv_rn(t2, zz.w), zz.z);
        float invz = __fadd_rn(__fadd_rn(u0, u1), u2);
        if (invz > 0.f) {
          float z = __fdiv_rn(1.0f, fmaxf(invz, 1e-12f));
          int fid = __float_as_int(M.z);
          unsigned long long ck = ((unsigned long long)__float_as_uint(z) << 32) | (unsigned)fid;
          if (ck < bestkey) { bestkey = ck; bestz = z; atomicMin(&sk[lane], ck); }
        }
      }
    }
    pos = nxt;
    M = Mn; bb = bbn;
  }
  atomicMin(&sk[lane], bestkey);
  __syncthreads();
  if (tid < 64) {
    unsigned long long k = sk[tid];
    unsigned zb = (unsigned)(k >> 32);
    o_idx[(size_t)b * (H_ * W_) + (size_t)y * W_ + seg * 64 + tid] =
        (zb >= 0x7f800000u) ? -1.0f : (float)(int)(unsigned)(k & 0xffffffffu);
  }
}

// ---------------- last-resort rasterizer (no workspace) ----------------
__global__ void k_raster_direct(const float* __restrict__ vpix, const int* __restrict__ vi,
                                float* __restrict__ idxout, int B, int V, int F) {
  int p = blockIdx.x * blockDim.x + threadIdx.x;
  if (p >= B * H_ * W_) return;
  int b = p / (H_ * W_); int pid = p - b * (H_ * W_);
  float px = (pid & (W_ - 1)) + 0.5f, py = (pid >> 8) + 0.5f;
  const float* base = vpix + (size_t)b * V * 3;
  float bestz = INFINITY; int besti = -1;
  for (int f = 0; f < F; ++f) {
    int i0 = vi[f * 3], i1 = vi[f * 3 + 1], i2 = vi[f * 3 + 2];
    float ax = base[(size_t)i0 * 3], ay = base[(size_t)i0 * 3 + 1], za = base[(size_t)i0 * 3 + 2];
    float bx = base[(size_t)i1 * 3], by = base[(size_t)i1 * 3 + 1], zb = base[(size_t)i1 * 3 + 2];
    float cx = base[(size_t)i2 * 3], cy = base[(size_t)i2 * 3 + 1], zc = base[(size_t)i2 * 3 + 2];
    float e0x = __fsub_rn(cx, bx), e0y = __fsub_rn(cy, by);
    float e1x = __fsub_rn(ax, cx), e1y = __fsub_rn(ay, cy);
    float e2x = __fsub_rn(bx, ax), e2y = __fsub_rn(by, ay);
    float area = __fsub_rn(__fmul_rn(e2x, __fsub_rn(cy, ay)), __fmul_rn(e2y, __fsub_rn(cx, ax)));
    float s = (area > 0.f) ? 1.f : ((area < 0.f) ? -1.f : 0.f);
    bool nz = fabsf(area) > 1e-8f;
    bool zv = (za > 0.f) && (zb > 0.f) && (zc > 0.f);
    float sp = (nz && zv) ? s : __uint_as_float(0x7fc00000u);
    float ar = nz ? area : 1.0f;
    float w0 = __fsub_rn(__fmul_rn(e0x, __fsub_rn(py, by)), __fmul_rn(e0y, __fsub_rn(px, bx)));
    float w1 = __fsub_rn(__fmul_rn(e1x, __fsub_rn(py, cy)), __fmul_rn(e1y, __fsub_rn(px, cx)));
    float w2 = __fsub_rn(__fmul_rn(e2x, __fsub_rn(py, ay)), __fmul_rn(e2y, __fsub_rn(px, ax)));
    bool inside = (__fmul_rn(w0, sp) >= 0.f) && (__fmul_rn(w1, sp) >= 0.f) && (__fmul_rn(w2, sp) >= 0.f);
    if (inside) {
      float invz = __fadd_rn(__fadd_rn(__fdiv_rn(__fdiv_rn(w0, ar), za),
                                       __fdiv_rn(__fdiv_rn(w1, ar), zb)),
                             __fdiv_rn(__fdiv_rn(w2, ar), zc));
      if (invz > 0.f) {
        float z = __fdiv_rn(1.0f, fmaxf(invz, 1e-12f));
        if (z < bestz) { bestz = z; besti = f; }
      }
    }
  }
  idxout[p] = (float)besti;
}

// ---------------- render + interpolate + grid_sample, fused ----------------
__global__ __launch_bounds__(256) void k_render(const float* __restrict__ vpix, const int* __restrict__ vi,
                                                const int* __restrict__ vti, const float* __restrict__ vt,
                                                const float* __restrict__ tex, const float* __restrict__ idxin,
                                                float* __restrict__ o_img, float* __restrict__ o_depth,
                                                float* __restrict__ o_vt, float* __restrict__ o_bary,
                                                float* __restrict__ o_mask,
                                                int B, int V, int F, int TH, int TW) {
  int p = blockIdx.x * blockDim.x + threadIdx.x;
  if (p >= B * H_ * W_) return;
  int HW = H_ * W_;
  int b = p / HW; int pid = p - b * HW;
  int y = pid >> 8, x = pid & (W_ - 1);
  int idx = (int)idxin[p];
  size_t pix2 = (size_t)b * 2 * HW + pid;
  size_t pix3 = (size_t)b * 3 * HW + pid;
  if (idx < 0) {
    o_depth[p] = 0.f; o_mask[p] = 0.f;
    o_vt[pix2] = 0.f; o_vt[pix2 + HW] = 0.f;
    o_bary[pix3] = 0.f; o_bary[pix3 + HW] = 0.f; o_bary[pix3 + 2 * HW] = 0.f;
    o_img[pix3] = 0.f; o_img[pix3 + HW] = 0.f; o_img[pix3 + 2 * HW] = 0.f;
    return;
  }
  const float* base = vpix + (size_t)b * V * 3;
  int i0 = vi[idx * 3], i1 = vi[idx * 3 + 1], i2 = vi[idx * 3 + 2];
  float ax = base[(size_t)i0 * 3], ay = base[(size_t)i0 * 3 + 1], az = base[(size_t)i0 * 3 + 2];
  float bx = base[(size_t)i1 * 3], by = base[(size_t)i1 * 3 + 1], bz = base[(size_t)i1 * 3 + 2];
  float cx = base[(size_t)i2 * 3], cy = base[(size_t)i2 * 3 + 1], cz = base[(size_t)i2 * 3 + 2];
  float ptx = x + 0.5f, pty = y + 0.5f;
  float w0 = __fsub_rn(__fmul_rn(__fsub_rn(cx, bx), __fsub_rn(pty, by)),
                       __fmul_rn(__fsub_rn(cy, by), __fsub_rn(ptx, bx)));
  float w1 = __fsub_rn(__fmul_rn(__fsub_rn(ax, cx), __fsub_rn(pty, cy)),
                       __fmul_rn(__fsub_rn(ay, cy), __fsub_rn(ptx, cx)));
  float w2 = __fsub_rn(__fmul_rn(__fsub_rn(bx, ax), __fsub_rn(pty, ay)),
                       __fmul_rn(__fsub_rn(by, ay), __fsub_rn(ptx, ax)));
  float area = __fadd_rn(__fadd_rn(w0, w1), w2);
  float ar = (fabsf(area) > 1e-8f) ? area : 1.0f;
  float f0 = __fdiv_rn(__fdiv_rn(w0, ar), fmaxf(az, 1e-8f));
  float f1 = __fdiv_rn(__fdiv_rn(w1, ar), fmaxf(bz, 1e-8f));
  float f2 = __fdiv_rn(__fdiv_rn(w2, ar), fmaxf(cz, 1e-8f));
  float invz = __fadd_rn(__fadd_rn(f0, f1), f2);
  float invz_s = (fabsf(invz) > 1e-12f) ? invz : 1.0f;
  float depth = __fdiv_rn(1.0f, invz_s);
  float bary0 = __fdiv_rn(f0, invz_s);
  float bary1 = __fdiv_rn(f1, invz_s);
  float bary2 = __fdiv_rn(f2, invz_s);
  o_depth[p] = depth; o_mask[p] = 1.0f;
  o_bary[pix3] = bary0; o_bary[pix3 + HW] = bary1; o_bary[pix3 + 2 * HW] = bary2;
  int t0 = vti[idx * 3], t1 = vti[idx * 3 + 1], t2 = vti[idx * 3 + 2];
  float u0x = __fsub_rn(__fmul_rn(vt[(size_t)t0 * 2], 2.f), 1.f);
  float u0y = __fsub_rn(__fmul_rn(vt[(size_t)t0 * 2 + 1], 2.f), 1.f);
  float u1x = __fsub_rn(__fmul_rn(vt[(size_t)t1 * 2], 2.f), 1.f);
  float u1y = __fsub_rn(__fmul_rn(vt[(size_t)t1 * 2 + 1], 2.f), 1.f);
  float u2x = __fsub_rn(__fmul_rn(vt[(size_t)t2 * 2], 2.f), 1.f);
  float u2y = __fsub_rn(__fmul_rn(vt[(size_t)t2 * 2 + 1], 2.f), 1.f);
  float gx = __fadd_rn(__fadd_rn(__fmul_rn(u0x, bary0), __fmul_rn(u1x, bary1)), __fmul_rn(u2x, bary2));
  float gy = __fadd_rn(__fadd_rn(__fmul_rn(u0y, bary0), __fmul_rn(u1y, bary1)), __fmul_rn(u2y, bary2));
  o_vt[pix2] = gx; o_vt[pix2 + HW] = gy;
  float sx = __fsub_rn(__fdiv_rn(__fmul_rn(__fadd_rn(gx, 1.0f), (float)TW), 2.0f), 0.5f);
  float sy = __fsub_rn(__fdiv_rn(__fmul_rn(__fadd_rn(gy, 1.0f), (float)TH), 2.0f), 0.5f);
  float x0f = floorf(sx), y0f = floorf(sy);
  float wx = __fsub_rn(sx, x0f), wy = __fsub_rn(sy, y0f);
  float omx = __fsub_rn(1.0f, wx), omy = __fsub_rn(1.0f, wy);
  int x0 = (int)x0f, y0 = (int)y0f;
  int x1 = x0 + 1, y1 = y0 + 1;
  bool v00 = (x0 >= 0) && (x0 < TW) && (y0 >= 0) && (y0 < TH);
  bool v10 = (x1 >= 0) && (x1 < TW) && (y0 >= 0) && (y0 < TH);
  bool v01 = (x0 >= 0) && (x0 < TW) && (y1 >= 0) && (y1 < TH);
  bool v11 = (x1 >= 0) && (x1 < TW) && (y1 >= 0) && (y1 < TH);
  int x0c = min(max(x0, 0), TW - 1), x1c = min(max(x1, 0), TW - 1);
  int y0c = min(max(y0, 0), TH - 1), y1c = min(max(y1, 0), TH - 1);
  const float* tb = tex + (size_t)b * 3 * TH * TW;
  #pragma unroll
  for (int ch = 0; ch < 3; ++ch) {
    const float* tc = tb + (size_t)ch * TH * TW;
    float g00 = v00 ? tc[(size_t)y0c * TW + x0c] : 0.f;
    float g10 = v10 ? tc[(size_t)y0c * TW + x1c] : 0.f;
    float g01 = v01 ? tc[(size_t)y1c * TW + x0c] : 0.f;
    float g11 = v11 ? tc[(size_t)y1c * TW + x1c] : 0.f;
    float r = __fmul_rn(__fmul_rn(g00, omx), omy);
    r = __fadd_rn(r, __fmul_rn(__fmul_rn(g10, wx), omy));
    r = __fadd_rn(r, __fmul_rn(__fmul_rn(g01, omx), wy));
    r = __fadd_rn(r, __fmul_rn(__fmul_rn(g11, wx), wy));
    o_img[pix3 + (size_t)ch * HW] = r;
  }
}

extern "C" void kernel_launch(void* const* d_in, const int* in_sizes, int n_in,
                              void* d_out, int out_size, void* d_ws, size_t ws_size,
                              hipStream_t stream) {
  const float* verts = (const float*)d_in[0];
  const float* tex   = (const float*)d_in[1];
  const float* Km    = (const float*)d_in[2];
  const float* Rt    = (const float*)d_in[3];
  const float* vt    = (const float*)d_in[4];
  const int*   vi    = (const int*)d_in[5];
  const int*   vti   = (const int*)d_in[6];

  int B = in_sizes[2] / 9;
  int V = in_sizes[0] / (3 * B);
  int F = in_sizes[5] / 3;
  long texhw = (long)in_sizes[1] / (B * 3);
  int TH = (int)(sqrt((double)texhw) + 0.5);
  int TW = TH;
  const int HW = H_ * W_;

  float* out = (float*)d_out;
  float* o_img   = out;
  float* o_depth = o_img + (size_t)B * 3 * HW;
  float* o_vpix  = o_depth + (size_t)B * HW;
  float* o_vt    = o_vpix + (size_t)B * V * 3;
  float* o_idx   = o_vt + (size_t)B * 2 * HW;
  float* o_bary  = o_idx + (size_t)B * HW;
  float* o_mask  = o_bary + (size_t)B * 3 * HW;

  k_transform<<<(B * V + 255) / 256, 256, 0, stream>>>(verts, Km, Rt, o_vpix, B, V);

  size_t f4Bytes    = (size_t)B * F * 16;
  size_t recBytes   = (size_t)B * F * REC_STRIDE * 4;
  size_t histBytes  = (size_t)B * NB * 4;
  size_t listBytes  = (size_t)B * NBAND * F * 64;   // inline 64B entries
  size_t cntBytes   = (size_t)B * NBAND * NB * 4;
  size_t bstBytes   = (size_t)B * NBAND * (NB + 1) * 4;
  size_t needBinned = 6 * f4Bytes + listBytes + recBytes + 3 * histBytes +
                      2 * cntBytes + bstBytes + 64;
  size_t needSorted = 6 * f4Bytes + recBytes + 3 * histBytes + 16;

  if (ws_size >= needSorted) {
    bool binned = (ws_size >= needBinned) && (F <= 65535);
    char* w = (char*)d_ws;
    float4* sA  = (float4*)w;  w += f4Bytes;
    float4* sB4 = (float4*)w;  w += f4Bytes;
    float4* sC  = (float4*)w;  w += f4Bytes;
    float4* sZ1 = (float4*)w;  w += f4Bytes;
    float4* sbb = (float4*)w;  w += f4Bytes;
    float4* sM  = (float4*)w;  w += f4Bytes;
    uint4*  list = nullptr;
    if (binned) { list = (uint4*)w; w += listBytes; }
    float*  rec = (float*)w;   w += recBytes;
    int*    hist = (int*)w;    w += histBytes;
    int*    boff = (int*)w;    w += histBytes;
    int*    cursor = (int*)w;  w += histBytes;
    int *cnt = nullptr, *bstart = nullptr, *bcur = nullptr;
    if (binned) {
      cnt = (int*)w;    w += cntBytes;
      bcur = (int*)w;   w += cntBytes;
      bstart = (int*)w; w += bstBytes;
    }
    unsigned* minmax = (unsigned*)w;

    int ninit = binned ? (B * NBAND * NB) : (B * NB);
    k_init<<<(ninit + 255) / 256, 256, 0, stream>>>(hist, cursor, B * NB,
                                                    cnt, bcur, binned ? B * NBAND * NB : 0, minmax);
    k_faceprep<<<(B * F + 255) / 256, 256, 0, stream>>>(o_vpix, vi, rec, minmax, B, V, F);
    k_hist<<<(B * F + 255) / 256, 256, 0, stream>>>(rec, minmax, hist, cnt, B, F);
    k_scan<<<1, NB, 0, stream>>>(hist, boff, B);
    if (binned) k_bandscan<<<B * NBAND, NB, 0, stream>>>(cnt, bstart);
    k_scatter<<<(B * F + 255) / 256, 256, 0, stream>>>(rec, minmax, boff, cursor,
                                                       sA, sB4, sC, sZ1, sbb, sM,
                                                       bstart, bcur, list, B, F);
    dim3 rg(W_ / 64, H_, B);
    if (binned)
      k_raster_band<<<rg, 64 * ILV, 0, stream>>>(list, bstart, sZ1, o_idx, B, F);
    else
      k_raster_tile<<<rg, 64 * ILV, 0, stream>>>(sA, sB4, sC, sZ1, sbb, sM, o_idx, B, F);
  } else {
    k_raster_direct<<<(B * HW + 255) / 256, 256, 0, stream>>>(o_vpix, vi, o_idx, B, V, F);
  }

  k_render<<<(B * HW + 255) / 256, 256, 0, stream>>>(o_vpix, vi, vti, vt, tex, o_idx,
                                                     o_img, o_depth, o_vt, o_bary, o_mask,
                                                     B, V, F, TH, TW);
}

// Round 8
// 380.565 us; speedup vs baseline: 1.5019x; 1.0851x over previous
//
#include <hip/hip_runtime.h>
#include <cmath>

#define H_ 256
#define W_ 256
#define NB 256           // zmin buckets
#define BANDSH 3         // log2(band height): 8-row bands
#define NBAND (H_ >> BANDSH)   // 32
#define ILV 4            // face-subset waves per tile block
#define INITKEY 0x7f800000FFFFFFFFull

__device__ inline unsigned fkey(float f) {
  unsigned u = __float_as_uint(f);
  return (u & 0x80000000u) ? ~u : (u | 0x80000000u);
}
__device__ inline float unfkey(unsigned k) {
  return (k & 0x80000000u) ? __uint_as_float(k & 0x7fffffffu) : __uint_as_float(~k);
}

__device__ inline int zbucket(float zmin, float zlo, float scale) {
  int bkt = 0;
  if (zmin == zmin) bkt = min(NB - 1, max(0, (int)((zmin - zlo) * scale)));
  return bkt;
}

// ---------------- transform ----------------
__global__ void k_transform(const float* __restrict__ verts, const float* __restrict__ Km,
                            const float* __restrict__ Rt, float* __restrict__ vpix,
                            int B, int V) {
  int i = blockIdx.x * blockDim.x + threadIdx.x;
  if (i >= B * V) return;
  int b = i / V;
  float x = verts[(size_t)i * 3 + 0], y = verts[(size_t)i * 3 + 1], z = verts[(size_t)i * 3 + 2];
  const float* R = Rt + (size_t)b * 12;
  float cx = __fadd_rn(__fadd_rn(__fadd_rn(__fmul_rn(R[0], x), __fmul_rn(R[1], y)), __fmul_rn(R[2], z)), R[3]);
  float cy = __fadd_rn(__fadd_rn(__fadd_rn(__fmul_rn(R[4], x), __fmul_rn(R[5], y)), __fmul_rn(R[6], z)), R[7]);
  float cz = __fadd_rn(__fadd_rn(__fadd_rn(__fmul_rn(R[8], x), __fmul_rn(R[9], y)), __fmul_rn(R[10], z)), R[11]);
  const float* Kb = Km + (size_t)b * 9;
  float px = __fadd_rn(__fadd_rn(__fmul_rn(Kb[0], cx), __fmul_rn(Kb[1], cy)), __fmul_rn(Kb[2], cz));
  float py = __fadd_rn(__fadd_rn(__fmul_rn(Kb[3], cx), __fmul_rn(Kb[4], cy)), __fmul_rn(Kb[5], cz));
  vpix[(size_t)i * 3 + 0] = __fdiv_rn(px, cz);
  vpix[(size_t)i * 3 + 1] = __fdiv_rn(py, cz);
  vpix[(size_t)i * 3 + 2] = cz;
}

// ---------------- init ----------------
__global__ void k_init(int* __restrict__ cnt, int* __restrict__ bcur, int n,
                       unsigned* __restrict__ minmax) {
  int i = blockIdx.x * blockDim.x + threadIdx.x;
  if (i < n) { cnt[i] = 0; bcur[i] = 0; }
  if (i == 0) { minmax[0] = 0xFFFFFFFFu; minmax[1] = 0u; }
}

// ---------------- per-face precompute: SoA in FACE order + meta + minmax ----------
// meta = {zmin, bbox_u8x4_bits, 0, 0}; invalid faces get bbox with xlo>xhi
__global__ void k_faceprep(const float* __restrict__ vpix, const int* __restrict__ vi,
                           float4* __restrict__ sA, float4* __restrict__ sB4,
                           float4* __restrict__ sC, float4* __restrict__ sZ1,
                           float4* __restrict__ meta, unsigned* __restrict__ minmax,
                           int B, int V, int F) {
  int i = blockIdx.x * blockDim.x + threadIdx.x;
  unsigned kmin = 0xFFFFFFFFu, kmax = 0u;
  if (i < B * F) {
    int b = i / F, f = i - b * F;
    int i0 = vi[f * 3 + 0], i1 = vi[f * 3 + 1], i2 = vi[f * 3 + 2];
    const float* base = vpix + (size_t)b * V * 3;
    float ax = base[(size_t)i0 * 3], ay = base[(size_t)i0 * 3 + 1], az = base[(size_t)i0 * 3 + 2];
    float bx = base[(size_t)i1 * 3], by = base[(size_t)i1 * 3 + 1], bz = base[(size_t)i1 * 3 + 2];
    float cx = base[(size_t)i2 * 3], cy = base[(size_t)i2 * 3 + 1], cz = base[(size_t)i2 * 3 + 2];
    float e0x = __fsub_rn(cx, bx), e0y = __fsub_rn(cy, by);
    float e1x = __fsub_rn(ax, cx), e1y = __fsub_rn(ay, cy);
    float e2x = __fsub_rn(bx, ax), e2y = __fsub_rn(by, ay);
    float area = __fsub_rn(__fmul_rn(e2x, __fsub_rn(cy, ay)), __fmul_rn(e2y, __fsub_rn(cx, ax)));
    float s = (area > 0.f) ? 1.f : ((area < 0.f) ? -1.f : 0.f);
    bool nz = fabsf(area) > 1e-8f;
    bool zv = (az > 0.f) && (bz > 0.f) && (cz > 0.f);
    float sp = (nz && zv) ? s : __uint_as_float(0x7fc00000u);  // NaN: invalid
    float ar = nz ? area : 1.0f;
    float zmin = fminf(az, fminf(bz, cz));
    // sp-prefolded edge records (IEEE-exact for sp=+-1; NaN propagates -> inside=false)
    sA[i]  = make_float4(ax, ay, bx, by);
    sB4[i] = make_float4(cx, cy, __fmul_rn(sp, e0x), __fmul_rn(sp, e0y));
    sC[i]  = make_float4(__fmul_rn(sp, e1x), __fmul_rn(sp, e1y),
                         __fmul_rn(sp, e2x), __fmul_rn(sp, e2y));
    sZ1[i] = make_float4(az, bz, cz, __fmul_rn(sp, ar));
    // integer pixel bbox (conservative-exact at pixel centers)
    unsigned bbox = 0x00000001u;  // xlo=1 > xhi=0: invalid sentinel
    if (sp == sp) {
      float minx = fminf(ax, fminf(bx, cx)), maxx = fmaxf(ax, fmaxf(bx, cx));
      float miny = fminf(ay, fminf(by, cy)), maxy = fmaxf(ay, fmaxf(by, cy));
      int xl = (int)ceilf(fmaxf(fminf(minx - 0.5f, 1e9f), -1e9f));
      int xh = (int)floorf(fmaxf(fminf(maxx - 0.5f, 1e9f), -1e9f));
      int yl = (int)ceilf(fmaxf(fminf(miny - 0.5f, 1e9f), -1e9f));
      int yh = (int)floorf(fmaxf(fminf(maxy - 0.5f, 1e9f), -1e9f));
      if (!(xl > xh || yl > yh || xh < 0 || xl > W_ - 1 || yh < 0 || yl > H_ - 1)) {
        int xlo = max(xl, 0), xhi = min(xh, W_ - 1);
        int ylo = max(yl, 0), yhi = min(yh, H_ - 1);
        bbox = (unsigned)xlo | ((unsigned)xhi << 8) | ((unsigned)ylo << 16) | ((unsigned)yhi << 24);
      }
    }
    meta[i] = make_float4(zmin, __uint_as_float(bbox), 0.f, 0.f);
    if (zmin == zmin) { kmin = fkey(zmin); kmax = kmin; }
  }
  // wave-reduced minmax (2 atomics per wave instead of 64)
  #pragma unroll
  for (int m = 32; m >= 1; m >>= 1) {
    kmin = min(kmin, (unsigned)__shfl_xor((int)kmin, m));
    kmax = max(kmax, (unsigned)__shfl_xor((int)kmax, m));
  }
  if ((threadIdx.x & 63) == 0) {
    atomicMin(&minmax[0], kmin);
    atomicMax(&minmax[1], kmax);
  }
}

// ---------------- per-(band,bucket) counting ----------------
__global__ void k_hist(const float4* __restrict__ meta, const unsigned* __restrict__ minmax,
                       int* __restrict__ cnt, int B, int F) {
  int i = blockIdx.x * blockDim.x + threadIdx.x;
  if (i >= B * F) return;
  int b = i / F;
  float4 m = meta[i];
  unsigned bbox = __float_as_uint(m.y);
  int xlo = (int)(bbox & 255u), xhi = (int)((bbox >> 8) & 255u);
  if (xlo > xhi) return;  // invalid
  float zlo = unfkey(minmax[0]), zhi = unfkey(minmax[1]);
  float scale = (float)NB / fmaxf(zhi - zlo, 1e-12f);
  int bkt = zbucket(m.x, zlo, scale);
  int ylo = (int)((bbox >> 16) & 255u), yhi = (int)(bbox >> 24);
  for (int band = (ylo >> BANDSH); band <= (yhi >> BANDSH); ++band)
    atomicAdd(&cnt[(b * NBAND + band) * NB + bkt], 1);
}

// per-(band) exclusive prefix over buckets; bstart[row][NB] = total length
__global__ void k_bandscan(const int* __restrict__ cnt, int* __restrict__ bstart) {
  __shared__ int sh[NB];
  int rowi = blockIdx.x;
  int t = threadIdx.x;
  sh[t] = cnt[rowi * NB + t];
  __syncthreads();
  int self = sh[t];
  for (int ofs = 1; ofs < NB; ofs <<= 1) {
    int u = (t >= ofs) ? sh[t - ofs] : 0;
    __syncthreads();
    sh[t] += u;
    __syncthreads();
  }
  bstart[rowi * (NB + 1) + t] = sh[t] - self;
  if (t == NB - 1) bstart[rowi * (NB + 1) + NB] = sh[t];
}

// ---------------- fill band lists: entry = {bbox, fid, zmin, zfloor} ----------------
__global__ void k_scatter(const float4* __restrict__ meta, const unsigned* __restrict__ minmax,
                          const int* __restrict__ bstart, int* __restrict__ bcur,
                          uint4* __restrict__ list, int B, int F) {
  int i = blockIdx.x * blockDim.x + threadIdx.x;
  if (i >= B * F) return;
  int b = i / F, f = i - b * F;
  float4 m = meta[i];
  unsigned bbox = __float_as_uint(m.y);
  int xlo = (int)(bbox & 255u), xhi = (int)((bbox >> 8) & 255u);
  if (xlo > xhi) return;  // invalid
  float zlo = unfkey(minmax[0]), zhi = unfkey(minmax[1]);
  float rng = fmaxf(zhi - zlo, 1e-12f);
  float scale = (float)NB / rng;
  int bkt = zbucket(m.x, zlo, scale);
  float floorval = zlo + (float)bkt * (rng / (float)NB);
  uint4 ent = make_uint4(bbox, (unsigned)f, __float_as_uint(m.x), __float_as_uint(floorval));
  int ylo = (int)((bbox >> 16) & 255u), yhi = (int)(bbox >> 24);
  for (int band = (ylo >> BANDSH); band <= (yhi >> BANDSH); ++band) {
    int rowi = b * NBAND + band;
    int slot = bstart[rowi * (NB + 1) + bkt] + atomicAdd(&bcur[rowi * NB + bkt], 1);
    list[(size_t)rowi * F + slot] = ent;
  }
}

// ---------------- band rasterizer (R6-measured structure, fid indexing) ----------------
__global__ __launch_bounds__(64 * ILV) void k_raster_band(const uint4* __restrict__ list,
                                                          const int* __restrict__ bstart,
                                                          const float4* __restrict__ sA,
                                                          const float4* __restrict__ sB4,
                                                          const float4* __restrict__ sC,
                                                          const float4* __restrict__ sZ1,
                                                          float* __restrict__ o_idx,
                                                          int B, int F) {
  int seg = blockIdx.x;
  int y   = blockIdx.y;
  int b   = blockIdx.z;
  int tid = threadIdx.x;
  int w = tid >> 6, lane = tid & 63;
  __shared__ unsigned long long sk[64];
  if (tid < 64) sk[tid] = INITKEY;
  __syncthreads();
  int rowi = b * NBAND + (y >> BANDSH);
  int len = bstart[rowi * (NB + 1) + NB];
  const uint4* L = list + (size_t)rowi * F;
  size_t fb = (size_t)b * F;
  float px = seg * 64 + lane + 0.5f, py = y + 0.5f;
  int sx0 = seg * 64, sx1 = sx0 + 63;
  unsigned long long bestkey = INITKEY;
  float bestz = INFINITY;
  int it = 0;
  int pos = w;
  uint4 e = (pos < len) ? L[pos] : make_uint4(0x00000001u, 0u, 0u, 0x7f800000u);
  while (pos < len) {
    int nxt = pos + ILV;
    uint4 en = L[(nxt < len) ? nxt : (len - 1)];  // meta needed unconditionally -> prefetch safe
    // break: bucket floor lower-bounds zmin of this and all later entries (bucket-ascending)
    float floor0 = __fmul_rn(__uint_as_float(e.w), 0.9999f) - 1e-5f;  // margin: never skips a tie
    if (__all(floor0 > bestz)) break;
    ++it;
    if ((it & 7) == 0) {  // periodic cross-wave exchange via LDS
      unsigned long long old = atomicMin(&sk[lane], bestkey);
      if (old < bestkey) { bestkey = old; bestz = __uint_as_float((unsigned)(bestkey >> 32)); }
    }
    int xlo = (int)(e.x & 255u), xhi = (int)((e.x >> 8) & 255u);
    int ylo = (int)((e.x >> 16) & 255u), yhi = (int)(e.x >> 24);
    bool cull = (y < ylo) || (y > yhi) || (xhi < sx0) || (xlo > sx1);
    if (!cull) {
      int f = (int)e.y;
      float4 a0 = sA[fb + f];
      float4 a1 = sB4[fb + f];
      float4 a2 = sC[fb + f];
      // t_i == w_i * sp bit-exactly (sp pre-folded; -0>=0 true, NaN false)
      float t0 = __fsub_rn(__fmul_rn(a1.z, __fsub_rn(py, a0.w)), __fmul_rn(a1.w, __fsub_rn(px, a0.z)));
      float t1 = __fsub_rn(__fmul_rn(a2.x, __fsub_rn(py, a1.y)), __fmul_rn(a2.y, __fsub_rn(px, a1.x)));
      float t2 = __fsub_rn(__fmul_rn(a2.z, __fsub_rn(py, a0.y)), __fmul_rn(a2.w, __fsub_rn(px, a0.x)));
      bool inside = (t0 >= 0.f) && (t1 >= 0.f) && (t2 >= 0.f);
      // divide-skip: zmin*0.9999 > bestz provably can't beat or tie
      if (inside && !(__fmul_rn(__uint_as_float(e.z), 0.9999f) > bestz)) {
        float4 zz = sZ1[fb + f];   // rare path only
        float u0 = __fdiv_rn(__fdiv_rn(t0, zz.w), zz.x);
        float u1 = __fdiv_rn(__fdiv_rn(t1, zz.w), zz.y);
        float u2 = __fdiv_rn(__fdiv_rn(t2, zz.w), zz.z);
        float invz = __fadd_rn(__fadd_rn(u0, u1), u2);
        if (invz > 0.f) {
          float z = __fdiv_rn(1.0f, fmaxf(invz, 1e-12f));
          unsigned long long ck = ((unsigned long long)__float_as_uint(z) << 32) | e.y;
          if (ck < bestkey) {
            bestkey = ck; bestz = z;
            atomicMin(&sk[lane], ck);  // push so other waves see it
          }
        }
      }
    }
    pos = nxt;
    e = en;
  }
  atomicMin(&sk[lane], bestkey);
  __syncthreads();
  if (tid < 64) {
    unsigned long long k = sk[tid];
    unsigned zb = (unsigned)(k >> 32);
    o_idx[(size_t)b * (H_ * W_) + (size_t)y * W_ + seg * 64 + tid] =
        (zb >= 0x7f800000u) ? -1.0f : (float)(int)(unsigned)(k & 0xffffffffu);
  }
}

// ---------------- last-resort rasterizer (no workspace) ----------------
__global__ void k_raster_direct(const float* __restrict__ vpix, const int* __restrict__ vi,
                                float* __restrict__ idxout, int B, int V, int F) {
  int p = blockIdx.x * blockDim.x + threadIdx.x;
  if (p >= B * H_ * W_) return;
  int b = p / (H_ * W_); int pid = p - b * (H_ * W_);
  float px = (pid & (W_ - 1)) + 0.5f, py = (pid >> 8) + 0.5f;
  const float* base = vpix + (size_t)b * V * 3;
  float bestz = INFINITY; int besti = -1;
  for (int f = 0; f < F; ++f) {
    int i0 = vi[f * 3], i1 = vi[f * 3 + 1], i2 = vi[f * 3 + 2];
    float ax = base[(size_t)i0 * 3], ay = base[(size_t)i0 * 3 + 1], za = base[(size_t)i0 * 3 + 2];
    float bx = base[(size_t)i1 * 3], by = base[(size_t)i1 * 3 + 1], zb = base[(size_t)i1 * 3 + 2];
    float cx = base[(size_t)i2 * 3], cy = base[(size_t)i2 * 3 + 1], zc = base[(size_t)i2 * 3 + 2];
    float e0x = __fsub_rn(cx, bx), e0y = __fsub_rn(cy, by);
    float e1x = __fsub_rn(ax, cx), e1y = __fsub_rn(ay, cy);
    float e2x = __fsub_rn(bx, ax), e2y = __fsub_rn(by, ay);
    float area = __fsub_rn(__fmul_rn(e2x, __fsub_rn(cy, ay)), __fmul_rn(e2y, __fsub_rn(cx, ax)));
    float s = (area > 0.f) ? 1.f : ((area < 0.f) ? -1.f : 0.f);
    bool nz = fabsf(area) > 1e-8f;
    bool zv = (za > 0.f) && (zb > 0.f) && (zc > 0.f);
    float sp = (nz && zv) ? s : __uint_as_float(0x7fc00000u);
    float ar = nz ? area : 1.0f;
    float w0 = __fsub_rn(__fmul_rn(e0x, __fsub_rn(py, by)), __fmul_rn(e0y, __fsub_rn(px, bx)));
    float w1 = __fsub_rn(__fmul_rn(e1x, __fsub_rn(py, cy)), __fmul_rn(e1y, __fsub_rn(px, cx)));
    float w2 = __fsub_rn(__fmul_rn(e2x, __fsub_rn(py, ay)), __fmul_rn(e2y, __fsub_rn(px, ax)));
    bool inside = (__fmul_rn(w0, sp) >= 0.f) && (__fmul_rn(w1, sp) >= 0.f) && (__fmul_rn(w2, sp) >= 0.f);
    if (inside) {
      float invz = __fadd_rn(__fadd_rn(__fdiv_rn(__fdiv_rn(w0, ar), za),
                                       __fdiv_rn(__fdiv_rn(w1, ar), zb)),
                             __fdiv_rn(__fdiv_rn(w2, ar), zc));
      if (invz > 0.f) {
        float z = __fdiv_rn(1.0f, fmaxf(invz, 1e-12f));
        if (z < bestz) { bestz = z; besti = f; }
      }
    }
  }
  idxout[p] = (float)besti;
}

// ---------------- render + interpolate + grid_sample, fused ----------------
__global__ __launch_bounds__(256) void k_render(const float* __restrict__ vpix, const int* __restrict__ vi,
                                                const int* __restrict__ vti, const float* __restrict__ vt,
                                                const float* __restrict__ tex, const float* __restrict__ idxin,
                                                float* __restrict__ o_img, float* __restrict__ o_depth,
                                                float* __restrict__ o_vt, float* __restrict__ o_bary,
                                                float* __restrict__ o_mask,
                                                int B, int V, int F, int TH, int TW) {
  int p = blockIdx.x * blockDim.x + threadIdx.x;
  if (p >= B * H_ * W_) return;
  int HW = H_ * W_;
  int b = p / HW; int pid = p - b * HW;
  int y = pid >> 8, x = pid & (W_ - 1);
  int idx = (int)idxin[p];
  size_t pix2 = (size_t)b * 2 * HW + pid;
  size_t pix3 = (size_t)b * 3 * HW + pid;
  if (idx < 0) {
    o_depth[p] = 0.f; o_mask[p] = 0.f;
    o_vt[pix2] = 0.f; o_vt[pix2 + HW] = 0.f;
    o_bary[pix3] = 0.f; o_bary[pix3 + HW] = 0.f; o_bary[pix3 + 2 * HW] = 0.f;
    o_img[pix3] = 0.f; o_img[pix3 + HW] = 0.f; o_img[pix3 + 2 * HW] = 0.f;
    return;
  }
  const float* base = vpix + (size_t)b * V * 3;
  int i0 = vi[idx * 3], i1 = vi[idx * 3 + 1], i2 = vi[idx * 3 + 2];
  float ax = base[(size_t)i0 * 3], ay = base[(size_t)i0 * 3 + 1], az = base[(size_t)i0 * 3 + 2];
  float bx = base[(size_t)i1 * 3], by = base[(size_t)i1 * 3 + 1], bz = base[(size_t)i1 * 3 + 2];
  float cx = base[(size_t)i2 * 3], cy = base[(size_t)i2 * 3 + 1], cz = base[(size_t)i2 * 3 + 2];
  float ptx = x + 0.5f, pty = y + 0.5f;
  float w0 = __fsub_rn(__fmul_rn(__fsub_rn(cx, bx), __fsub_rn(pty, by)),
                       __fmul_rn(__fsub_rn(cy, by), __fsub_rn(ptx, bx)));
  float w1 = __fsub_rn(__fmul_rn(__fsub_rn(ax, cx), __fsub_rn(pty, cy)),
                       __fmul_rn(__fsub_rn(ay, cy), __fsub_rn(ptx, cx)));
  float w2 = __fsub_rn(__fmul_rn(__fsub_rn(bx, ax), __fsub_rn(pty, ay)),
                       __fmul_rn(__fsub_rn(by, ay), __fsub_rn(ptx, ax)));
  float area = __fadd_rn(__fadd_rn(w0, w1), w2);
  float ar = (fabsf(area) > 1e-8f) ? area : 1.0f;
  float f0 = __fdiv_rn(__fdiv_rn(w0, ar), fmaxf(az, 1e-8f));
  float f1 = __fdiv_rn(__fdiv_rn(w1, ar), fmaxf(bz, 1e-8f));
  float f2 = __fdiv_rn(__fdiv_rn(w2, ar), fmaxf(cz, 1e-8f));
  float invz = __fadd_rn(__fadd_rn(f0, f1), f2);
  float invz_s = (fabsf(invz) > 1e-12f) ? invz : 1.0f;
  float depth = __fdiv_rn(1.0f, invz_s);
  float bary0 = __fdiv_rn(f0, invz_s);
  float bary1 = __fdiv_rn(f1, invz_s);
  float bary2 = __fdiv_rn(f2, invz_s);
  o_depth[p] = depth; o_mask[p] = 1.0f;
  o_bary[pix3] = bary0; o_bary[pix3 + HW] = bary1; o_bary[pix3 + 2 * HW] = bary2;
  int t0 = vti[idx * 3], t1 = vti[idx * 3 + 1], t2 = vti[idx * 3 + 2];
  float u0x = __fsub_rn(__fmul_rn(vt[(size_t)t0 * 2], 2.f), 1.f);
  float u0y = __fsub_rn(__fmul_rn(vt[(size_t)t0 * 2 + 1], 2.f), 1.f);
  float u1x = __fsub_rn(__fmul_rn(vt[(size_t)t1 * 2], 2.f), 1.f);
  float u1y = __fsub_rn(__fmul_rn(vt[(size_t)t1 * 2 + 1], 2.f), 1.f);
  float u2x = __fsub_rn(__fmul_rn(vt[(size_t)t2 * 2], 2.f), 1.f);
  float u2y = __fsub_rn(__fmul_rn(vt[(size_t)t2 * 2 + 1], 2.f), 1.f);
  float gx = __fadd_rn(__fadd_rn(__fmul_rn(u0x, bary0), __fmul_rn(u1x, bary1)), __fmul_rn(u2x, bary2));
  float gy = __fadd_rn(__fadd_rn(__fmul_rn(u0y, bary0), __fmul_rn(u1y, bary1)), __fmul_rn(u2y, bary2));
  o_vt[pix2] = gx; o_vt[pix2 + HW] = gy;
  float sx = __fsub_rn(__fdiv_rn(__fmul_rn(__fadd_rn(gx, 1.0f), (float)TW), 2.0f), 0.5f);
  float sy = __fsub_rn(__fdiv_rn(__fmul_rn(__fadd_rn(gy, 1.0f), (float)TH), 2.0f), 0.5f);
  float x0f = floorf(sx), y0f = floorf(sy);
  float wx = __fsub_rn(sx, x0f), wy = __fsub_rn(sy, y0f);
  float omx = __fsub_rn(1.0f, wx), omy = __fsub_rn(1.0f, wy);
  int x0 = (int)x0f, y0 = (int)y0f;
  int x1 = x0 + 1, y1 = y0 + 1;
  bool v00 = (x0 >= 0) && (x0 < TW) && (y0 >= 0) && (y0 < TH);
  bool v10 = (x1 >= 0) && (x1 < TW) && (y0 >= 0) && (y0 < TH);
  bool v01 = (x0 >= 0) && (x0 < TW) && (y1 >= 0) && (y1 < TH);
  bool v11 = (x1 >= 0) && (x1 < TW) && (y1 >= 0) && (y1 < TH);
  int x0c = min(max(x0, 0), TW - 1), x1c = min(max(x1, 0), TW - 1);
  int y0c = min(max(y0, 0), TH - 1), y1c = min(max(y1, 0), TH - 1);
  const float* tb = tex + (size_t)b * 3 * TH * TW;
  #pragma unroll
  for (int ch = 0; ch < 3; ++ch) {
    const float* tc = tb + (size_t)ch * TH * TW;
    float g00 = v00 ? tc[(size_t)y0c * TW + x0c] : 0.f;
    float g10 = v10 ? tc[(size_t)y0c * TW + x1c] : 0.f;
    float g01 = v01 ? tc[(size_t)y1c * TW + x0c] : 0.f;
    float g11 = v11 ? tc[(size_t)y1c * TW + x1c] : 0.f;
    float r = __fmul_rn(__fmul_rn(g00, omx), omy);
    r = __fadd_rn(r, __fmul_rn(__fmul_rn(g10, wx), omy));
    r = __fadd_rn(r, __fmul_rn(__fmul_rn(g01, omx), wy));
    r = __fadd_rn(r, __fmul_rn(__fmul_rn(g11, wx), wy));
    o_img[pix3 + (size_t)ch * HW] = r;
  }
}

extern "C" void kernel_launch(void* const* d_in, const int* in_sizes, int n_in,
                              void* d_out, int out_size, void* d_ws, size_t ws_size,
                              hipStream_t stream) {
  const float* verts = (const float*)d_in[0];
  const float* tex   = (const float*)d_in[1];
  const float* Km    = (const float*)d_in[2];
  const float* Rt    = (const float*)d_in[3];
  const float* vt    = (const float*)d_in[4];
  const int*   vi    = (const int*)d_in[5];
  const int*   vti   = (const int*)d_in[6];

  int B = in_sizes[2] / 9;
  int V = in_sizes[0] / (3 * B);
  int F = in_sizes[5] / 3;
  long texhw = (long)in_sizes[1] / (B * 3);
  int TH = (int)(sqrt((double)texhw) + 0.5);
  int TW = TH;
  const int HW = H_ * W_;

  float* out = (float*)d_out;
  float* o_img   = out;
  float* o_depth = o_img + (size_t)B * 3 * HW;
  float* o_vpix  = o_depth + (size_t)B * HW;
  float* o_vt    = o_vpix + (size_t)B * V * 3;
  float* o_idx   = o_vt + (size_t)B * 2 * HW;
  float* o_bary  = o_idx + (size_t)B * HW;
  float* o_mask  = o_bary + (size_t)B * 3 * HW;

  k_transform<<<(B * V + 255) / 256, 256, 0, stream>>>(verts, Km, Rt, o_vpix, B, V);

  size_t f4Bytes   = (size_t)B * F * 16;
  size_t listBytes = (size_t)B * NBAND * F * 16;
  size_t cntBytes  = (size_t)B * NBAND * NB * 4;
  size_t bstBytes  = (size_t)B * NBAND * (NB + 1) * 4;
  size_t need = 5 * f4Bytes + listBytes + 2 * cntBytes + bstBytes + 64;

  if (ws_size >= need) {
    char* w = (char*)d_ws;
    float4* sA   = (float4*)w;  w += f4Bytes;
    float4* sB4  = (float4*)w;  w += f4Bytes;
    float4* sC   = (float4*)w;  w += f4Bytes;
    float4* sZ1  = (float4*)w;  w += f4Bytes;
    float4* meta = (float4*)w;  w += f4Bytes;
    uint4*  list = (uint4*)w;   w += listBytes;
    int*    cnt  = (int*)w;     w += cntBytes;
    int*    bcur = (int*)w;     w += cntBytes;
    int*    bst  = (int*)w;     w += bstBytes;
    unsigned* minmax = (unsigned*)w;

    int ninit = B * NBAND * NB;
    k_init<<<(ninit + 255) / 256, 256, 0, stream>>>(cnt, bcur, ninit, minmax);
    k_faceprep<<<(B * F + 255) / 256, 256, 0, stream>>>(o_vpix, vi, sA, sB4, sC, sZ1,
                                                        meta, minmax, B, V, F);
    k_hist<<<(B * F + 255) / 256, 256, 0, stream>>>(meta, minmax, cnt, B, F);
    k_bandscan<<<B * NBAND, NB, 0, stream>>>(cnt, bst);
    k_scatter<<<(B * F + 255) / 256, 256, 0, stream>>>(meta, minmax, bst, bcur, list, B, F);
    dim3 rg(W_ / 64, H_, B);
    k_raster_band<<<rg, 64 * ILV, 0, stream>>>(list, bst, sA, sB4, sC, sZ1, o_idx, B, F);
  } else {
    k_raster_direct<<<(B * HW + 255) / 256, 256, 0, stream>>>(o_vpix, vi, o_idx, B, V, F);
  }

  k_render<<<(B * HW + 255) / 256, 256, 0, stream>>>(o_vpix, vi, vti, vt, tex, o_idx,
                                                     o_img, o_depth, o_vt, o_bary, o_mask,
                                                     B, V, F, TH, TW);
}

// Round 9
// 367.307 us; speedup vs baseline: 1.5561x; 1.0361x over previous
//
#include <hip/hip_runtime.h>
#include <cmath>

#define H_ 256
#define W_ 256
#define NB 256           // zmin buckets
#define BANDSH 3         // log2(band height): 8-row bands
#define NBAND (H_ >> BANDSH)   // 32
#define ILV 4            // face-subset waves per tile block
#define INITKEY 0x7f800000FFFFFFFFull

__device__ inline unsigned fkey(float f) {
  unsigned u = __float_as_uint(f);
  return (u & 0x80000000u) ? ~u : (u | 0x80000000u);
}
__device__ inline float unfkey(unsigned k) {
  return (k & 0x80000000u) ? __uint_as_float(k & 0x7fffffffu) : __uint_as_float(~k);
}

__device__ inline int zbucket(float zmin, float zlo, float scale) {
  int bkt = 0;
  if (zmin == zmin) bkt = min(NB - 1, max(0, (int)((zmin - zlo) * scale)));
  return bkt;
}

// ---------------- transform (+ vertex-z minmax for bucket range) ----------------
__global__ void k_transform(const float* __restrict__ verts, const float* __restrict__ Km,
                            const float* __restrict__ Rt, float* __restrict__ vpix,
                            unsigned* __restrict__ minmax, int B, int V) {
  int i = blockIdx.x * blockDim.x + threadIdx.x;
  unsigned kmin = 0xFFFFFFFFu, kmax = 0u;
  if (i < B * V) {
    int b = i / V;
    float x = verts[(size_t)i * 3 + 0], y = verts[(size_t)i * 3 + 1], z = verts[(size_t)i * 3 + 2];
    const float* R = Rt + (size_t)b * 12;
    float cx = __fadd_rn(__fadd_rn(__fadd_rn(__fmul_rn(R[0], x), __fmul_rn(R[1], y)), __fmul_rn(R[2], z)), R[3]);
    float cy = __fadd_rn(__fadd_rn(__fadd_rn(__fmul_rn(R[4], x), __fmul_rn(R[5], y)), __fmul_rn(R[6], z)), R[7]);
    float cz = __fadd_rn(__fadd_rn(__fadd_rn(__fmul_rn(R[8], x), __fmul_rn(R[9], y)), __fmul_rn(R[10], z)), R[11]);
    const float* Kb = Km + (size_t)b * 9;
    float px = __fadd_rn(__fadd_rn(__fmul_rn(Kb[0], cx), __fmul_rn(Kb[1], cy)), __fmul_rn(Kb[2], cz));
    float py = __fadd_rn(__fadd_rn(__fmul_rn(Kb[3], cx), __fmul_rn(Kb[4], cy)), __fmul_rn(Kb[5], cz));
    vpix[(size_t)i * 3 + 0] = __fdiv_rn(px, cz);
    vpix[(size_t)i * 3 + 1] = __fdiv_rn(py, cz);
    vpix[(size_t)i * 3 + 2] = cz;
    if (minmax && cz == cz) { kmin = fkey(cz); kmax = kmin; }
  }
  if (minmax) {
    #pragma unroll
    for (int m = 32; m >= 1; m >>= 1) {
      kmin = min(kmin, (unsigned)__shfl_xor((int)kmin, m));
      kmax = max(kmax, (unsigned)__shfl_xor((int)kmax, m));
    }
    if ((threadIdx.x & 63) == 0) {
      atomicMin(&minmax[0], kmin);
      atomicMax(&minmax[1], kmax);
    }
  }
}

// ---------------- init (runs before transform: minmax must be ready) ----------------
__global__ void k_init(int* __restrict__ cnt, int* __restrict__ bcur, int n,
                       unsigned* __restrict__ minmax) {
  int i = blockIdx.x * blockDim.x + threadIdx.x;
  if (i < n) { cnt[i] = 0; bcur[i] = 0; }
  if (i == 0) { minmax[0] = 0xFFFFFFFFu; minmax[1] = 0u; }
}

// ---------------- per-face precompute + fused band-bucket hist ----------------
// meta = {zmin, packbits(segmask|ylo<<8|yhi<<16), bkt_bits, floorval}; invalid: pack=0
__global__ void k_faceprep(const float* __restrict__ vpix, const int* __restrict__ vi,
                           const int* __restrict__ vti, const float* __restrict__ vt,
                           float4* __restrict__ sA, float4* __restrict__ sB4,
                           float4* __restrict__ sC, float4* __restrict__ sZ1,
                           float4* __restrict__ sE1, float4* __restrict__ sE2,
                           float4* __restrict__ sUV12, float4* __restrict__ sUV2,
                           float4* __restrict__ meta, const unsigned* __restrict__ minmax,
                           int* __restrict__ cnt, int B, int V, int F) {
  int i = blockIdx.x * blockDim.x + threadIdx.x;
  if (i >= B * F) return;
  int b = i / F, f = i - b * F;
  int i0 = vi[f * 3 + 0], i1 = vi[f * 3 + 1], i2 = vi[f * 3 + 2];
  const float* base = vpix + (size_t)b * V * 3;
  float ax = base[(size_t)i0 * 3], ay = base[(size_t)i0 * 3 + 1], az = base[(size_t)i0 * 3 + 2];
  float bx = base[(size_t)i1 * 3], by = base[(size_t)i1 * 3 + 1], bz = base[(size_t)i1 * 3 + 2];
  float cx = base[(size_t)i2 * 3], cy = base[(size_t)i2 * 3 + 1], cz = base[(size_t)i2 * 3 + 2];
  float e0x = __fsub_rn(cx, bx), e0y = __fsub_rn(cy, by);
  float e1x = __fsub_rn(ax, cx), e1y = __fsub_rn(ay, cy);
  float e2x = __fsub_rn(bx, ax), e2y = __fsub_rn(by, ay);
  float area = __fsub_rn(__fmul_rn(e2x, __fsub_rn(cy, ay)), __fmul_rn(e2y, __fsub_rn(cx, ax)));
  float s = (area > 0.f) ? 1.f : ((area < 0.f) ? -1.f : 0.f);
  bool nz = fabsf(area) > 1e-8f;
  bool zv = (az > 0.f) && (bz > 0.f) && (cz > 0.f);
  float sp = (nz && zv) ? s : __uint_as_float(0x7fc00000u);  // NaN: invalid
  float ar = nz ? area : 1.0f;
  float zmin = fminf(az, fminf(bz, cz));
  // raster records (sp-prefolded edges: IEEE-exact for sp=+-1; NaN -> inside=false)
  sA[i]  = make_float4(ax, ay, bx, by);
  sB4[i] = make_float4(cx, cy, __fmul_rn(sp, e0x), __fmul_rn(sp, e0y));
  sC[i]  = make_float4(__fmul_rn(sp, e1x), __fmul_rn(sp, e1y),
                       __fmul_rn(sp, e2x), __fmul_rn(sp, e2y));
  sZ1[i] = make_float4(az, bz, cz, __fmul_rn(sp, ar));
  // render records (RAW edges — identical bits to inline recompute)
  sE1[i] = make_float4(cx, cy, e0x, e0y);
  sE2[i] = make_float4(e1x, e1y, e2x, e2y);
  int t0 = vti[f * 3], t1 = vti[f * 3 + 1], t2 = vti[f * 3 + 2];
  float u0x = __fsub_rn(__fmul_rn(vt[(size_t)t0 * 2], 2.f), 1.f);
  float u0y = __fsub_rn(__fmul_rn(vt[(size_t)t0 * 2 + 1], 2.f), 1.f);
  float u1x = __fsub_rn(__fmul_rn(vt[(size_t)t1 * 2], 2.f), 1.f);
  float u1y = __fsub_rn(__fmul_rn(vt[(size_t)t1 * 2 + 1], 2.f), 1.f);
  float u2x = __fsub_rn(__fmul_rn(vt[(size_t)t2 * 2], 2.f), 1.f);
  float u2y = __fsub_rn(__fmul_rn(vt[(size_t)t2 * 2 + 1], 2.f), 1.f);
  sUV12[i] = make_float4(u0x, u0y, u1x, u1y);
  sUV2[i]  = make_float4(u2x, u2y, 0.f, 0.f);
  // integer pixel bbox (conservative-exact at pixel centers) -> packed cull word
  unsigned pack = 0u;   // 0 = invalid (empty segmask)
  int bkt = 0; float floorval = 0.f;
  float zlo = unfkey(minmax[0]), zhi = unfkey(minmax[1]);
  float rng = fmaxf(zhi - zlo, 1e-12f);
  float scale = (float)NB / rng;
  if (sp == sp) {
    float minx = fminf(ax, fminf(bx, cx)), maxx = fmaxf(ax, fmaxf(bx, cx));
    float miny = fminf(ay, fminf(by, cy)), maxy = fmaxf(ay, fmaxf(by, cy));
    int xl = (int)ceilf(fmaxf(fminf(minx - 0.5f, 1e9f), -1e9f));
    int xh = (int)floorf(fmaxf(fminf(maxx - 0.5f, 1e9f), -1e9f));
    int yl = (int)ceilf(fmaxf(fminf(miny - 0.5f, 1e9f), -1e9f));
    int yh = (int)floorf(fmaxf(fminf(maxy - 0.5f, 1e9f), -1e9f));
    if (!(xl > xh || yl > yh || xh < 0 || xl > W_ - 1 || yh < 0 || yl > H_ - 1)) {
      int xlo = max(xl, 0), xhi = min(xh, W_ - 1);
      int ylo = max(yl, 0), yhi = min(yh, H_ - 1);
      unsigned segmask = (((1u << ((xhi >> 6) + 1)) - 1u) & ~((1u << (xlo >> 6)) - 1u)) & 0xFu;
      pack = segmask | ((unsigned)ylo << 8) | ((unsigned)yhi << 16);
      bkt = zbucket(zmin, zlo, scale);
      floorval = zlo + (float)bkt * (rng / (float)NB);
      for (int band = (ylo >> BANDSH); band <= (yhi >> BANDSH); ++band)
        atomicAdd(&cnt[(b * NBAND + band) * NB + bkt], 1);
    }
  }
  meta[i] = make_float4(zmin, __uint_as_float(pack), __int_as_float(bkt), floorval);
}

// per-(band) exclusive prefix over buckets; bstart[row][NB] = total length
__global__ void k_bandscan(const int* __restrict__ cnt, int* __restrict__ bstart) {
  __shared__ int sh[NB];
  int rowi = blockIdx.x;
  int t = threadIdx.x;
  sh[t] = cnt[rowi * NB + t];
  __syncthreads();
  int self = sh[t];
  for (int ofs = 1; ofs < NB; ofs <<= 1) {
    int u = (t >= ofs) ? sh[t - ofs] : 0;
    __syncthreads();
    sh[t] += u;
    __syncthreads();
  }
  bstart[rowi * (NB + 1) + t] = sh[t] - self;
  if (t == NB - 1) bstart[rowi * (NB + 1) + NB] = sh[t];
}

// ---------------- fill band lists: entry = {pack, fid, zmin, zfloor} ----------------
__global__ void k_scatter(const float4* __restrict__ meta,
                          const int* __restrict__ bstart, int* __restrict__ bcur,
                          uint4* __restrict__ list, int B, int F) {
  int i = blockIdx.x * blockDim.x + threadIdx.x;
  if (i >= B * F) return;
  int b = i / F, f = i - b * F;
  float4 m = meta[i];
  unsigned pack = __float_as_uint(m.y);
  if ((pack & 0xFu) == 0u) return;  // invalid / off-screen
  int bkt = __float_as_int(m.z);
  uint4 ent = make_uint4(pack, (unsigned)f, __float_as_uint(m.x), __float_as_uint(m.w));
  int ylo = (int)((pack >> 8) & 255u), yhi = (int)((pack >> 16) & 255u);
  for (int band = (ylo >> BANDSH); band <= (yhi >> BANDSH); ++band) {
    int rowi = b * NBAND + band;
    int slot = bstart[rowi * (NB + 1) + bkt] + atomicAdd(&bcur[rowi * NB + bkt], 1);
    list[(size_t)rowi * F + slot] = ent;
  }
}

// ---------------- band rasterizer (R8 structure + scalarized entry) ----------------
__global__ __launch_bounds__(64 * ILV) void k_raster_band(const uint4* __restrict__ list,
                                                          const int* __restrict__ bstart,
                                                          const float4* __restrict__ sA,
                                                          const float4* __restrict__ sB4,
                                                          const float4* __restrict__ sC,
                                                          const float4* __restrict__ sZ1,
                                                          float* __restrict__ o_idx,
                                                          int B, int F) {
  int seg = blockIdx.x;
  int y   = blockIdx.y;
  int b   = blockIdx.z;
  int tid = threadIdx.x;
  int w = tid >> 6, lane = tid & 63;
  __shared__ unsigned long long sk[64];
  if (tid < 64) sk[tid] = INITKEY;
  __syncthreads();
  int rowi = b * NBAND + (y >> BANDSH);
  int len = bstart[rowi * (NB + 1) + NB];
  const uint4* L = list + (size_t)rowi * F;
  size_t fb = (size_t)b * F;
  float px = seg * 64 + lane + 0.5f, py = y + 0.5f;
  unsigned long long bestkey = INITKEY;
  float bestz = INFINITY;
  int it = 0;
  int pos = w;
  uint4 e = (pos < len) ? L[pos] : make_uint4(0u, 0u, 0u, 0x7f800000u);
  while (pos < len) {
    int nxt = pos + ILV;
    uint4 en = L[(nxt < len) ? nxt : (len - 1)];  // meta needed unconditionally -> prefetch safe
    // scalarize the wave-uniform entry -> scalar branches, scalar record loads
    unsigned pack = __builtin_amdgcn_readfirstlane(e.x);
    int      fid  = __builtin_amdgcn_readfirstlane((int)e.y);
    float    zmn  = __uint_as_float(__builtin_amdgcn_readfirstlane(e.z));
    float    zfl  = __uint_as_float(__builtin_amdgcn_readfirstlane(e.w));
    // break: bucket floor lower-bounds zmin of this and all later entries (bucket-ascending)
    float floor0 = __fmul_rn(zfl, 0.9999f) - 1e-5f;  // margin: never skips a tie
    if (__all(floor0 > bestz)) break;
    ++it;
    if ((it & 7) == 0) {  // periodic cross-wave exchange via LDS
      unsigned long long old = atomicMin(&sk[lane], bestkey);
      if (old < bestkey) { bestkey = old; bestz = __uint_as_float((unsigned)(bestkey >> 32)); }
    }
    bool cull = !((pack >> seg) & 1u) ||
                (y < (int)((pack >> 8) & 255u)) || (y > (int)((pack >> 16) & 255u));
    if (!cull) {
      float4 a0 = sA[fb + fid];
      float4 a1 = sB4[fb + fid];
      float4 a2 = sC[fb + fid];
      // t_i == w_i * sp bit-exactly (sp pre-folded; -0>=0 true, NaN false)
      float t0 = __fsub_rn(__fmul_rn(a1.z, __fsub_rn(py, a0.w)), __fmul_rn(a1.w, __fsub_rn(px, a0.z)));
      float t1 = __fsub_rn(__fmul_rn(a2.x, __fsub_rn(py, a1.y)), __fmul_rn(a2.y, __fsub_rn(px, a1.x)));
      float t2 = __fsub_rn(__fmul_rn(a2.z, __fsub_rn(py, a0.y)), __fmul_rn(a2.w, __fsub_rn(px, a0.x)));
      bool inside = (t0 >= 0.f) && (t1 >= 0.f) && (t2 >= 0.f);
      // divide-skip: zmin*0.9999 > bestz provably can't beat or tie
      if (inside && !(__fmul_rn(zmn, 0.9999f) > bestz)) {
        float4 zz = sZ1[fb + fid];   // rare path only
        float u0 = __fdiv_rn(__fdiv_rn(t0, zz.w), zz.x);
        float u1 = __fdiv_rn(__fdiv_rn(t1, zz.w), zz.y);
        float u2 = __fdiv_rn(__fdiv_rn(t2, zz.w), zz.z);
        float invz = __fadd_rn(__fadd_rn(u0, u1), u2);
        if (invz > 0.f) {
          float z = __fdiv_rn(1.0f, fmaxf(invz, 1e-12f));
          unsigned long long ck = ((unsigned long long)__float_as_uint(z) << 32) | (unsigned)fid;
          if (ck < bestkey) {
            bestkey = ck; bestz = z;
            atomicMin(&sk[lane], ck);  // push so other waves see it
          }
        }
      }
    }
    pos = nxt;
    e = en;
  }
  atomicMin(&sk[lane], bestkey);
  __syncthreads();
  if (tid < 64) {
    unsigned long long k = sk[tid];
    unsigned zb = (unsigned)(k >> 32);
    o_idx[(size_t)b * (H_ * W_) + (size_t)y * W_ + seg * 64 + tid] =
        (zb >= 0x7f800000u) ? -1.0f : (float)(int)(unsigned)(k & 0xffffffffu);
  }
}

// ---------------- last-resort rasterizer (no workspace) ----------------
__global__ void k_raster_direct(const float* __restrict__ vpix, const int* __restrict__ vi,
                                float* __restrict__ idxout, int B, int V, int F) {
  int p = blockIdx.x * blockDim.x + threadIdx.x;
  if (p >= B * H_ * W_) return;
  int b = p / (H_ * W_); int pid = p - b * (H_ * W_);
  float px = (pid & (W_ - 1)) + 0.5f, py = (pid >> 8) + 0.5f;
  const float* base = vpix + (size_t)b * V * 3;
  float bestz = INFINITY; int besti = -1;
  for (int f = 0; f < F; ++f) {
    int i0 = vi[f * 3], i1 = vi[f * 3 + 1], i2 = vi[f * 3 + 2];
    float ax = base[(size_t)i0 * 3], ay = base[(size_t)i0 * 3 + 1], za = base[(size_t)i0 * 3 + 2];
    float bx = base[(size_t)i1 * 3], by = base[(size_t)i1 * 3 + 1], zb = base[(size_t)i1 * 3 + 2];
    float cx = base[(size_t)i2 * 3], cy = base[(size_t)i2 * 3 + 1], zc = base[(size_t)i2 * 3 + 2];
    float e0x = __fsub_rn(cx, bx), e0y = __fsub_rn(cy, by);
    float e1x = __fsub_rn(ax, cx), e1y = __fsub_rn(ay, cy);
    float e2x = __fsub_rn(bx, ax), e2y = __fsub_rn(by, ay);
    float area = __fsub_rn(__fmul_rn(e2x, __fsub_rn(cy, ay)), __fmul_rn(e2y, __fsub_rn(cx, ax)));
    float s = (area > 0.f) ? 1.f : ((area < 0.f) ? -1.f : 0.f);
    bool nz = fabsf(area) > 1e-8f;
    bool zv = (za > 0.f) && (zb > 0.f) && (zc > 0.f);
    float sp = (nz && zv) ? s : __uint_as_float(0x7fc00000u);
    float ar = nz ? area : 1.0f;
    float w0 = __fsub_rn(__fmul_rn(e0x, __fsub_rn(py, by)), __fmul_rn(e0y, __fsub_rn(px, bx)));
    float w1 = __fsub_rn(__fmul_rn(e1x, __fsub_rn(py, cy)), __fmul_rn(e1y, __fsub_rn(px, cx)));
    float w2 = __fsub_rn(__fmul_rn(e2x, __fsub_rn(py, ay)), __fmul_rn(e2y, __fsub_rn(px, ax)));
    bool inside = (__fmul_rn(w0, sp) >= 0.f) && (__fmul_rn(w1, sp) >= 0.f) && (__fmul_rn(w2, sp) >= 0.f);
    if (inside) {
      float invz = __fadd_rn(__fadd_rn(__fdiv_rn(__fdiv_rn(w0, ar), za),
                                       __fdiv_rn(__fdiv_rn(w1, ar), zb)),
                             __fdiv_rn(__fdiv_rn(w2, ar), zc));
      if (invz > 0.f) {
        float z = __fdiv_rn(1.0f, fmaxf(invz, 1e-12f));
        if (z < bestz) { bestz = z; besti = f; }
      }
    }
  }
  idxout[p] = (float)besti;
}

// ---------------- render from face records (6 float4 gathers + tex) ----------------
__global__ __launch_bounds__(256) void k_render_rec(const float4* __restrict__ sA,
                                                    const float4* __restrict__ sE1,
                                                    const float4* __restrict__ sE2,
                                                    const float4* __restrict__ sZ1,
                                                    const float4* __restrict__ sUV12,
                                                    const float4* __restrict__ sUV2,
                                                    const float* __restrict__ tex,
                                                    const float* __restrict__ idxin,
                                                    float* __restrict__ o_img, float* __restrict__ o_depth,
                                                    float* __restrict__ o_vt, float* __restrict__ o_bary,
                                                    float* __restrict__ o_mask,
                                                    int B, int F, int TH, int TW) {
  int p = blockIdx.x * blockDim.x + threadIdx.x;
  if (p >= B * H_ * W_) return;
  int HW = H_ * W_;
  int b = p / HW; int pid = p - b * HW;
  int y = pid >> 8, x = pid & (W_ - 1);
  int idx = (int)idxin[p];
  size_t pix2 = (size_t)b * 2 * HW + pid;
  size_t pix3 = (size_t)b * 3 * HW + pid;
  if (idx < 0) {
    o_depth[p] = 0.f; o_mask[p] = 0.f;
    o_vt[pix2] = 0.f; o_vt[pix2 + HW] = 0.f;
    o_bary[pix3] = 0.f; o_bary[pix3 + HW] = 0.f; o_bary[pix3 + 2 * HW] = 0.f;
    o_img[pix3] = 0.f; o_img[pix3 + HW] = 0.f; o_img[pix3 + 2 * HW] = 0.f;
    return;
  }
  size_t gp = (size_t)b * F + idx;
  float4 a0 = sA[gp];    // ax,ay,bx,by
  float4 e1 = sE1[gp];   // cx,cy,e0x,e0y (raw)
  float4 e2 = sE2[gp];   // e1x,e1y,e2x,e2y (raw)
  float4 zz = sZ1[gp];   // az,bz,cz,-
  float4 uv = sUV12[gp];
  float4 uv2 = sUV2[gp];
  float ptx = x + 0.5f, pty = y + 0.5f;
  float w0 = __fsub_rn(__fmul_rn(e1.z, __fsub_rn(pty, a0.w)), __fmul_rn(e1.w, __fsub_rn(ptx, a0.z)));
  float w1 = __fsub_rn(__fmul_rn(e2.x, __fsub_rn(pty, e1.y)), __fmul_rn(e2.y, __fsub_rn(ptx, e1.x)));
  float w2 = __fsub_rn(__fmul_rn(e2.z, __fsub_rn(pty, a0.y)), __fmul_rn(e2.w, __fsub_rn(ptx, a0.x)));
  float area = __fadd_rn(__fadd_rn(w0, w1), w2);
  float ar = (fabsf(area) > 1e-8f) ? area : 1.0f;
  float f0 = __fdiv_rn(__fdiv_rn(w0, ar), fmaxf(zz.x, 1e-8f));
  float f1 = __fdiv_rn(__fdiv_rn(w1, ar), fmaxf(zz.y, 1e-8f));
  float f2 = __fdiv_rn(__fdiv_rn(w2, ar), fmaxf(zz.z, 1e-8f));
  float invz = __fadd_rn(__fadd_rn(f0, f1), f2);
  float invz_s = (fabsf(invz) > 1e-12f) ? invz : 1.0f;
  float depth = __fdiv_rn(1.0f, invz_s);
  float bary0 = __fdiv_rn(f0, invz_s);
  float bary1 = __fdiv_rn(f1, invz_s);
  float bary2 = __fdiv_rn(f2, invz_s);
  o_depth[p] = depth; o_mask[p] = 1.0f;
  o_bary[pix3] = bary0; o_bary[pix3 + HW] = bary1; o_bary[pix3 + 2 * HW] = bary2;
  float gx = __fadd_rn(__fadd_rn(__fmul_rn(uv.x, bary0), __fmul_rn(uv.z, bary1)), __fmul_rn(uv2.x, bary2));
  float gy = __fadd_rn(__fadd_rn(__fmul_rn(uv.y, bary0), __fmul_rn(uv.w, bary1)), __fmul_rn(uv2.y, bary2));
  o_vt[pix2] = gx; o_vt[pix2 + HW] = gy;
  float sx = __fsub_rn(__fdiv_rn(__fmul_rn(__fadd_rn(gx, 1.0f), (float)TW), 2.0f), 0.5f);
  float sy = __fsub_rn(__fdiv_rn(__fmul_rn(__fadd_rn(gy, 1.0f), (float)TH), 2.0f), 0.5f);
  float x0f = floorf(sx), y0f = floorf(sy);
  float wx = __fsub_rn(sx, x0f), wy = __fsub_rn(sy, y0f);
  float omx = __fsub_rn(1.0f, wx), omy = __fsub_rn(1.0f, wy);
  int x0 = (int)x0f, y0 = (int)y0f;
  int x1 = x0 + 1, y1 = y0 + 1;
  bool v00 = (x0 >= 0) && (x0 < TW) && (y0 >= 0) && (y0 < TH);
  bool v10 = (x1 >= 0) && (x1 < TW) && (y0 >= 0) && (y0 < TH);
  bool v01 = (x0 >= 0) && (x0 < TW) && (y1 >= 0) && (y1 < TH);
  bool v11 = (x1 >= 0) && (x1 < TW) && (y1 >= 0) && (y1 < TH);
  int x0c = min(max(x0, 0), TW - 1), x1c = min(max(x1, 0), TW - 1);
  int y0c = min(max(y0, 0), TH - 1), y1c = min(max(y1, 0), TH - 1);
  const float* tb = tex + (size_t)b * 3 * TH * TW;
  #pragma unroll
  for (int ch = 0; ch < 3; ++ch) {
    const float* tc = tb + (size_t)ch * TH * TW;
    float g00 = v00 ? tc[(size_t)y0c * TW + x0c] : 0.f;
    float g10 = v10 ? tc[(size_t)y0c * TW + x1c] : 0.f;
    float g01 = v01 ? tc[(size_t)y1c * TW + x0c] : 0.f;
    float g11 = v11 ? tc[(size_t)y1c * TW + x1c] : 0.f;
    float r = __fmul_rn(__fmul_rn(g00, omx), omy);
    r = __fadd_rn(r, __fmul_rn(__fmul_rn(g10, wx), omy));
    r = __fadd_rn(r, __fmul_rn(__fmul_rn(g01, omx), wy));
    r = __fadd_rn(r, __fmul_rn(__fmul_rn(g11, wx), wy));
    o_img[pix3 + (size_t)ch * HW] = r;
  }
}

// ---------------- fallback render (per-pixel gathers, no records) ----------------
__global__ __launch_bounds__(256) void k_render(const float* __restrict__ vpix, const int* __restrict__ vi,
                                                const int* __restrict__ vti, const float* __restrict__ vt,
                                                const float* __restrict__ tex, const float* __restrict__ idxin,
                                                float* __restrict__ o_img, float* __restrict__ o_depth,
                                                float* __restrict__ o_vt, float* __restrict__ o_bary,
                                                float* __restrict__ o_mask,
                                                int B, int V, int F, int TH, int TW) {
  int p = blockIdx.x * blockDim.x + threadIdx.x;
  if (p >= B * H_ * W_) return;
  int HW = H_ * W_;
  int b = p / HW; int pid = p - b * HW;
  int y = pid >> 8, x = pid & (W_ - 1);
  int idx = (int)idxin[p];
  size_t pix2 = (size_t)b * 2 * HW + pid;
  size_t pix3 = (size_t)b * 3 * HW + pid;
  if (idx < 0) {
    o_depth[p] = 0.f; o_mask[p] = 0.f;
    o_vt[pix2] = 0.f; o_vt[pix2 + HW] = 0.f;
    o_bary[pix3] = 0.f; o_bary[pix3 + HW] = 0.f; o_bary[pix3 + 2 * HW] = 0.f;
    o_img[pix3] = 0.f; o_img[pix3 + HW] = 0.f; o_img[pix3 + 2 * HW] = 0.f;
    return;
  }
  const float* base = vpix + (size_t)b * V * 3;
  int i0 = vi[idx * 3], i1 = vi[idx * 3 + 1], i2 = vi[idx * 3 + 2];
  float ax = base[(size_t)i0 * 3], ay = base[(size_t)i0 * 3 + 1], az = base[(size_t)i0 * 3 + 2];
  float bx = base[(size_t)i1 * 3], by = base[(size_t)i1 * 3 + 1], bz = base[(size_t)i1 * 3 + 2];
  float cx = base[(size_t)i2 * 3], cy = base[(size_t)i2 * 3 + 1], cz = base[(size_t)i2 * 3 + 2];
  float ptx = x + 0.5f, pty = y + 0.5f;
  float w0 = __fsub_rn(__fmul_rn(__fsub_rn(cx, bx), __fsub_rn(pty, by)),
                       __fmul_rn(__fsub_rn(cy, by), __fsub_rn(ptx, bx)));
  float w1 = __fsub_rn(__fmul_rn(__fsub_rn(ax, cx), __fsub_rn(pty, cy)),
                       __fmul_rn(__fsub_rn(ay, cy), __fsub_rn(ptx, cx)));
  float w2 = __fsub_rn(__fmul_rn(__fsub_rn(bx, ax), __fsub_rn(pty, ay)),
                       __fmul_rn(__fsub_rn(by, ay), __fsub_rn(ptx, ax)));
  float area = __fadd_rn(__fadd_rn(w0, w1), w2);
  float ar = (fabsf(area) > 1e-8f) ? area : 1.0f;
  float f0 = __fdiv_rn(__fdiv_rn(w0, ar), fmaxf(az, 1e-8f));
  float f1 = __fdiv_rn(__fdiv_rn(w1, ar), fmaxf(bz, 1e-8f));
  float f2 = __fdiv_rn(__fdiv_rn(w2, ar), fmaxf(cz, 1e-8f));
  float invz = __fadd_rn(__fadd_rn(f0, f1), f2);
  float invz_s = (fabsf(invz) > 1e-12f) ? invz : 1.0f;
  float depth = __fdiv_rn(1.0f, invz_s);
  float bary0 = __fdiv_rn(f0, invz_s);
  float bary1 = __fdiv_rn(f1, invz_s);
  float bary2 = __fdiv_rn(f2, invz_s);
  o_depth[p] = depth; o_mask[p] = 1.0f;
  o_bary[pix3] = bary0; o_bary[pix3 + HW] = bary1; o_bary[pix3 + 2 * HW] = bary2;
  int t0 = vti[idx * 3], t1 = vti[idx * 3 + 1], t2 = vti[idx * 3 + 2];
  float u0x = __fsub_rn(__fmul_rn(vt[(size_t)t0 * 2], 2.f), 1.f);
  float u0y = __fsub_rn(__fmul_rn(vt[(size_t)t0 * 2 + 1], 2.f), 1.f);
  float u1x = __fsub_rn(__fmul_rn(vt[(size_t)t1 * 2], 2.f), 1.f);
  float u1y = __fsub_rn(__fmul_rn(vt[(size_t)t1 * 2 + 1], 2.f), 1.f);
  float u2x = __fsub_rn(__fmul_rn(vt[(size_t)t2 * 2], 2.f), 1.f);
  float u2y = __fsub_rn(__fmul_rn(vt[(size_t)t2 * 2 + 1], 2.f), 1.f);
  float gx = __fadd_rn(__fadd_rn(__fmul_rn(u0x, bary0), __fmul_rn(u1x, bary1)), __fmul_rn(u2x, bary2));
  float gy = __fadd_rn(__fadd_rn(__fmul_rn(u0y, bary0), __fmul_rn(u1y, bary1)), __fmul_rn(u2y, bary2));
  o_vt[pix2] = gx; o_vt[pix2 + HW] = gy;
  float sx = __fsub_rn(__fdiv_rn(__fmul_rn(__fadd_rn(gx, 1.0f), (float)TW), 2.0f), 0.5f);
  float sy = __fsub_rn(__fdiv_rn(__fmul_rn(__fadd_rn(gy, 1.0f), (float)TH), 2.0f), 0.5f);
  float x0f = floorf(sx), y0f = floorf(sy);
  float wx = __fsub_rn(sx, x0f), wy = __fsub_rn(sy, y0f);
  float omx = __fsub_rn(1.0f, wx), omy = __fsub_rn(1.0f, wy);
  int x0 = (int)x0f, y0 = (int)y0f;
  int x1 = x0 + 1, y1 = y0 + 1;
  bool v00 = (x0 >= 0) && (x0 < TW) && (y0 >= 0) && (y0 < TH);
  bool v10 = (x1 >= 0) && (x1 < TW) && (y0 >= 0) && (y0 < TH);
  bool v01 = (x0 >= 0) && (x0 < TW) && (y1 >= 0) && (y1 < TH);
  bool v11 = (x1 >= 0) && (x1 < TW) && (y1 >= 0) && (y1 < TH);
  int x0c = min(max(x0, 0), TW - 1), x1c = min(max(x1, 0), TW - 1);
  int y0c = min(max(y0, 0), TH - 1), y1c = min(max(y1, 0), TH - 1);
  const float* tb = tex + (size_t)b * 3 * TH * TW;
  #pragma unroll
  for (int ch = 0; ch < 3; ++ch) {
    const float* tc = tb + (size_t)ch * TH * TW;
    float g00 = v00 ? tc[(size_t)y0c * TW + x0c] : 0.f;
    float g10 = v10 ? tc[(size_t)y0c * TW + x1c] : 0.f;
    float g01 = v01 ? tc[(size_t)y1c * TW + x0c] : 0.f;
    float g11 = v11 ? tc[(size_t)y1c * TW + x1c] : 0.f;
    float r = __fmul_rn(__fmul_rn(g00, omx), omy);
    r = __fadd_rn(r, __fmul_rn(__fmul_rn(g10, wx), omy));
    r = __fadd_rn(r, __fmul_rn(__fmul_rn(g01, omx), wy));
    r = __fadd_rn(r, __fmul_rn(__fmul_rn(g11, wx), wy));
    o_img[pix3 + (size_t)ch * HW] = r;
  }
}

extern "C" void kernel_launch(void* const* d_in, const int* in_sizes, int n_in,
                              void* d_out, int out_size, void* d_ws, size_t ws_size,
                              hipStream_t stream) {
  const float* verts = (const float*)d_in[0];
  const float* tex   = (const float*)d_in[1];
  const float* Km    = (const float*)d_in[2];
  const float* Rt    = (const float*)d_in[3];
  const float* vt    = (const float*)d_in[4];
  const int*   vi    = (const int*)d_in[5];
  const int*   vti   = (const int*)d_in[6];

  int B = in_sizes[2] / 9;
  int V = in_sizes[0] / (3 * B);
  int F = in_sizes[5] / 3;
  long texhw = (long)in_sizes[1] / (B * 3);
  int TH = (int)(sqrt((double)texhw) + 0.5);
  int TW = TH;
  const int HW = H_ * W_;

  float* out = (float*)d_out;
  float* o_img   = out;
  float* o_depth = o_img + (size_t)B * 3 * HW;
  float* o_vpix  = o_depth + (size_t)B * HW;
  float* o_vt    = o_vpix + (size_t)B * V * 3;
  float* o_idx   = o_vt + (size_t)B * 2 * HW;
  float* o_bary  = o_idx + (size_t)B * HW;
  float* o_mask  = o_bary + (size_t)B * 3 * HW;

  size_t f4Bytes   = (size_t)B * F * 16;
  size_t listBytes = (size_t)B * NBAND * F * 16;
  size_t cntBytes  = (size_t)B * NBAND * NB * 4;
  size_t bstBytes  = (size_t)B * NBAND * (NB + 1) * 4;
  size_t need = 9 * f4Bytes + listBytes + 2 * cntBytes + bstBytes + 64;

  if (ws_size >= need) {
    char* w = (char*)d_ws;
    float4* sA    = (float4*)w;  w += f4Bytes;
    float4* sB4   = (float4*)w;  w += f4Bytes;
    float4* sC    = (float4*)w;  w += f4Bytes;
    float4* sZ1   = (float4*)w;  w += f4Bytes;
    float4* sE1   = (float4*)w;  w += f4Bytes;
    float4* sE2   = (float4*)w;  w += f4Bytes;
    float4* sUV12 = (float4*)w;  w += f4Bytes;
    float4* sUV2  = (float4*)w;  w += f4Bytes;
    float4* meta  = (float4*)w;  w += f4Bytes;
    uint4*  list  = (uint4*)w;   w += listBytes;
    int*    cnt   = (int*)w;     w += cntBytes;
    int*    bcur  = (int*)w;     w += cntBytes;
    int*    bst   = (int*)w;     w += bstBytes;
    unsigned* minmax = (unsigned*)w;

    int ninit = B * NBAND * NB;
    k_init<<<(ninit + 255) / 256, 256, 0, stream>>>(cnt, bcur, ninit, minmax);
    k_transform<<<(B * V + 255) / 256, 256, 0, stream>>>(verts, Km, Rt, o_vpix, minmax, B, V);
    k_faceprep<<<(B * F + 255) / 256, 256, 0, stream>>>(o_vpix, vi, vti, vt,
                                                        sA, sB4, sC, sZ1, sE1, sE2, sUV12, sUV2,
                                                        meta, minmax, cnt, B, V, F);
    k_bandscan<<<B * NBAND, NB, 0, stream>>>(cnt, bst);
    k_scatter<<<(B * F + 255) / 256, 256, 0, stream>>>(meta, bst, bcur, list, B, F);
    dim3 rg(W_ / 64, H_, B);
    k_raster_band<<<rg, 64 * ILV, 0, stream>>>(list, bst, sA, sB4, sC, sZ1, o_idx, B, F);
    k_render_rec<<<(B * HW + 255) / 256, 256, 0, stream>>>(sA, sE1, sE2, sZ1, sUV12, sUV2,
                                                           tex, o_idx,
                                                           o_img, o_depth, o_vt, o_bary, o_mask,
                                                           B, F, TH, TW);
  } else {
    k_transform<<<(B * V + 255) / 256, 256, 0, stream>>>(verts, Km, Rt, o_vpix,
                                                         (unsigned*)nullptr, B, V);
    k_raster_direct<<<(B * HW + 255) / 256, 256, 0, stream>>>(o_vpix, vi, o_idx, B, V, F);
    k_render<<<(B * HW + 255) / 256, 256, 0, stream>>>(o_vpix, vi, vti, vt, tex, o_idx,
                                                       o_img, o_depth, o_vt, o_bary, o_mask,
                                                       B, V, F, TH, TW);
  }
}